// Round 10
// baseline (307.797 us; speedup 1.0000x reference)
//
#include <hip/hip_runtime.h>
#include <cstdint>
#include <cstddef>

#define NTOK 8192
#define NEXP 8
#define CAP 1280
#define CDIM 768
#define IDIM 3072
#define EROWS (NEXP*CAP)   /* 10240 */

typedef __attribute__((ext_vector_type(8))) short short8;
typedef __attribute__((ext_vector_type(4))) float f32x4;
typedef __attribute__((ext_vector_type(4))) unsigned short us4;
typedef __attribute__((ext_vector_type(8))) unsigned short us8;

__device__ __forceinline__ unsigned short f2b(float f) {
  unsigned u = __builtin_bit_cast(unsigned, f);
  u += 0x7FFFu + ((u >> 16) & 1u);          // round-to-nearest-even
  return (unsigned short)(u >> 16);
}
__device__ __forceinline__ float b2f(unsigned short u) {
  return __builtin_bit_cast(float, ((unsigned)u) << 16);
}

// ---------------- 64x64 vectorized transpose + f32->bf16 (Wp) ----------------
__global__ __launch_bounds__(256) void transpose_cvt64(const float* __restrict__ src,
    unsigned short* __restrict__ dst, int R, int S) {
  int tilesS = S >> 6, tilesR = R >> 6;
  int perE = tilesR * tilesS;
  int e = blockIdx.x / perE;
  int rem = blockIdx.x % perE;
  int rt = rem / tilesS, st = rem % tilesS;
  const float* se = src + (size_t)e*R*S + ((size_t)rt*64)*S + st*64;
  unsigned short* de = dst + (size_t)e*R*S + ((size_t)st*64)*R + rt*64;
  __shared__ float tile[64][65];
  int c4 = (threadIdx.x & 15)*4, rr = threadIdx.x >> 4;   // rr 0..15
#pragma unroll
  for (int p = 0; p < 4; ++p) {
    float4 v = *(const float4*)(se + (size_t)(rr + 16*p)*S + c4);
    tile[rr + 16*p][c4+0] = v.x; tile[rr + 16*p][c4+1] = v.y;
    tile[rr + 16*p][c4+2] = v.z; tile[rr + 16*p][c4+3] = v.w;
  }
  __syncthreads();
#pragma unroll
  for (int p = 0; p < 4; ++p) {
    int s = rr + 16*p;
    us4 o;
    o.x = f2b(tile[c4+0][s]); o.y = f2b(tile[c4+1][s]);
    o.z = f2b(tile[c4+2][s]); o.w = f2b(tile[c4+3][s]);
    *(us4*)(de + (size_t)s*R + c4) = o;
  }
}

// ---------------- Wg+Wu -> interleaved-transposed combined Wgu (64x64) -------
__global__ __launch_bounds__(256) void wgu_cvt64(const float* __restrict__ Wg,
    const float* __restrict__ Wu, unsigned short* __restrict__ Wgu) {
  const int tilesR = CDIM/64, tilesS = IDIM/64;    // 12, 48
  const int perE = tilesR * tilesS;
  int sel = blockIdx.x / (NEXP*perE);
  int rem = blockIdx.x % (NEXP*perE);
  int e = rem / perE; int r2 = rem % perE;
  int rt = r2 / tilesS, st = r2 % tilesS;
  const float* se = (sel ? Wu : Wg) + (size_t)e*CDIM*IDIM + ((size_t)rt*64)*IDIM + st*64;
  __shared__ float tile[64][65];
  int c4 = (threadIdx.x & 15)*4, rr = threadIdx.x >> 4;
#pragma unroll
  for (int p = 0; p < 4; ++p) {
    float4 v = *(const float4*)(se + (size_t)(rr + 16*p)*IDIM + c4);
    tile[rr + 16*p][c4+0] = v.x; tile[rr + 16*p][c4+1] = v.y;
    tile[rr + 16*p][c4+2] = v.z; tile[rr + 16*p][c4+3] = v.w;
  }
  __syncthreads();
  unsigned short* dstE = Wgu + (size_t)e*(2*IDIM)*CDIM;
#pragma unroll
  for (int p = 0; p < 4; ++p) {
    int s = rr + 16*p;
    int np = 128*st + 32*(s>>4) + (s&15) + sel*16;
    us4 o;
    o.x = f2b(tile[c4+0][s]); o.y = f2b(tile[c4+1][s]);
    o.z = f2b(tile[c4+2][s]); o.w = f2b(tile[c4+3][s]);
    *(us4*)(dstE + (size_t)np*CDIM + rt*64 + c4) = o;
  }
}

// ---------------- router ----------------
__global__ __launch_bounds__(256) void router_kernel(const float* __restrict__ x,
    const float* __restrict__ Wr, float* __restrict__ probs,
    int* __restrict__ idx1, int* __restrict__ idx2,
    float* __restrict__ g1r, float* __restrict__ g2r) {
  __shared__ float WrT[NEXP*CDIM];
  for (int i = threadIdx.x; i < NEXP*CDIM; i += 256) {
    int c = i >> 3, e = i & 7;
    WrT[e*CDIM + c] = Wr[i];
  }
  __syncthreads();
  int w = threadIdx.x >> 6, l = threadIdx.x & 63;
  int t = blockIdx.x*4 + w;
  float acc[NEXP];
#pragma unroll
  for (int e = 0; e < NEXP; ++e) acc[e] = 0.f;
  for (int k = 0; k < CDIM/64; ++k) {
    float xv = x[(size_t)t*CDIM + k*64 + l];
#pragma unroll
    for (int e = 0; e < NEXP; ++e) acc[e] += xv * WrT[e*CDIM + k*64 + l];
  }
#pragma unroll
  for (int off = 32; off > 0; off >>= 1) {
#pragma unroll
    for (int e = 0; e < NEXP; ++e) acc[e] += __shfl_xor(acc[e], off);
  }
  if (l == 0) {
    float m = acc[0];
#pragma unroll
    for (int e = 1; e < NEXP; ++e) m = fmaxf(m, acc[e]);
    float p[NEXP]; float s = 0.f;
#pragma unroll
    for (int e = 0; e < NEXP; ++e) { p[e] = expf(acc[e] - m); s += p[e]; }
    float inv = 1.f / s;
#pragma unroll
    for (int e = 0; e < NEXP; ++e) { p[e] *= inv; probs[(size_t)t*NEXP + e] = p[e]; }
    int i1 = 0; float b1 = p[0];
#pragma unroll
    for (int e = 1; e < NEXP; ++e) if (p[e] > b1) { b1 = p[e]; i1 = e; }
    int i2 = -1; float b2 = -1e30f;
#pragma unroll
    for (int e = 0; e < NEXP; ++e) if (e != i1 && p[e] > b2) { b2 = p[e]; i2 = e; }
    float gs = fmaxf(b1 + b2, 1e-9f);
    g1r[t] = b1 / gs; g2r[t] = b2 / gs;
    idx1[t] = i1; idx2[t] = i2;
  }
}

// ---------------- scan ----------------
__global__ __launch_bounds__(1024) void scan_kernel(
    const int* __restrict__ idx1, const int* __restrict__ idx2,
    const float* __restrict__ g1r, const float* __restrict__ g2r,
    const float* __restrict__ probs,
    int* __restrict__ bufmap,
    int* __restrict__ c1o, int* __restrict__ c2o,
    float* __restrict__ g1o, float* __restrict__ g2o,
    float* __restrict__ aux_out) {
  __shared__ unsigned int scanbuf[1024][9];
  __shared__ unsigned int totals[NEXP];
  int tid = threadIdx.x;
  int e1[8], e2[8];
  unsigned int cnt[NEXP];
#pragma unroll
  for (int k = 0; k < NEXP; ++k) cnt[k] = 0;
  for (int j = 0; j < 8; ++j) {
    int t = tid*8 + j;
    e1[j] = idx1[t]; e2[j] = idx2[t];
    cnt[e1[j]] += 1u;
    cnt[e2[j]] += (1u << 16);
  }
#pragma unroll
  for (int k = 0; k < NEXP; ++k) scanbuf[tid][k] = cnt[k];
  unsigned int run[NEXP];
#pragma unroll
  for (int k = 0; k < NEXP; ++k) run[k] = cnt[k];
  __syncthreads();
  for (int off = 1; off < 1024; off <<= 1) {
    unsigned int add[NEXP];
#pragma unroll
    for (int k = 0; k < NEXP; ++k) add[k] = 0;
    if (tid >= off) {
#pragma unroll
      for (int k = 0; k < NEXP; ++k) add[k] = scanbuf[tid - off][k];
    }
    __syncthreads();
#pragma unroll
    for (int k = 0; k < NEXP; ++k) { run[k] += add[k]; scanbuf[tid][k] = run[k]; }
    __syncthreads();
  }
  if (tid == 1023) {
#pragma unroll
    for (int k = 0; k < NEXP; ++k) totals[k] = run[k];
  }
  __syncthreads();
  unsigned int excl[NEXP];
#pragma unroll
  for (int k = 0; k < NEXP; ++k) excl[k] = run[k] - cnt[k];
  int cnt1c[NEXP];
#pragma unroll
  for (int k = 0; k < NEXP; ++k) cnt1c[k] = min((int)(totals[k] & 0xFFFFu), CAP);

  for (int j = 0; j < 8; ++j) {
    int t = tid*8 + j;
    int a = e1[j];
    int pos1 = (int)(excl[a] & 0xFFFFu); excl[a] += 1u;
    int slot1 = a*CAP + pos1;
    bool m1 = pos1 < CAP;
    if (m1) bufmap[slot1] = t;
    int b = e2[j];
    int pos2 = (int)(excl[b] >> 16) + cnt1c[b]; excl[b] += (1u << 16);
    int slot2 = b*CAP + pos2;
    bool m2 = pos2 < CAP;
    if (m2) bufmap[slot2] = t;
    float G1 = m1 ? g1r[t] : 0.f;
    float G2 = m2 ? g2r[t] : 0.f;
    float den = fmaxf(G1 + G2, 1e-9f);
    g1o[t] = G1 / den; g2o[t] = G2 / den;
    c1o[t] = min(slot1, EROWS - 1);
    c2o[t] = min(slot2, EROWS - 1);
  }

  float imp[NEXP];
#pragma unroll
  for (int k = 0; k < NEXP; ++k) imp[k] = 0.f;
  for (int j = 0; j < 8; ++j) {
    int t = tid*8 + j;
    const float4* pr = (const float4*)(probs + (size_t)t*NEXP);
    float4 a0 = pr[0], a1 = pr[1];
    imp[0] += a0.x; imp[1] += a0.y; imp[2] += a0.z; imp[3] += a0.w;
    imp[4] += a1.x; imp[5] += a1.y; imp[6] += a1.z; imp[7] += a1.w;
  }
  __syncthreads();
  float* fbuf = (float*)&scanbuf[0][0];
#pragma unroll
  for (int k = 0; k < NEXP; ++k) fbuf[tid*9 + k] = imp[k];
  __syncthreads();
  for (int s = 512; s >= 1; s >>= 1) {
    if (tid < s) {
#pragma unroll
      for (int k = 0; k < NEXP; ++k) fbuf[tid*9 + k] += fbuf[(tid + s)*9 + k];
    }
    __syncthreads();
  }
  if (tid == 0) {
    float aux = 0.f;
#pragma unroll
    for (int k = 0; k < NEXP; ++k) {
      float importance = fbuf[k] / (float)NTOK;
      float loadk = (float)((totals[k] & 0xFFFFu) + (totals[k] >> 16)) / ((float)NTOK * 2.0f);
      aux += importance * loadk;
    }
    aux_out[0] = aux * (float)NEXP * 0.01f;
  }
}

// ---------------- dispatch ----------------
__global__ __launch_bounds__(192) void dispatch_kernel(const float* __restrict__ x,
    const int* __restrict__ bufmap, unsigned short* __restrict__ ein) {
  int r = blockIdx.x;
  int t = bufmap[r];
  int q = threadIdx.x;
  float4 v = make_float4(0.f, 0.f, 0.f, 0.f);
  if (t >= 0) v = ((const float4*)x)[(size_t)t*(CDIM/4) + q];
  us4 o;
  o.x = f2b(v.x); o.y = f2b(v.y); o.z = f2b(v.z); o.w = f2b(v.w);
  ((us4*)ein)[(size_t)r*(CDIM/4) + q] = o;
}

#define BAR  asm volatile("s_barrier" ::: "memory")
#define VMW(N) asm volatile("s_waitcnt vmcnt(" #N ")" ::: "memory")
#define LGW  asm volatile("s_waitcnt lgkmcnt(0)" ::: "memory")
#define P1 __builtin_amdgcn_s_setprio(1)
#define P0 __builtin_amdgcn_s_setprio(0)

// =============== GEMM1: persistent 4-phase 256x128, 8 output tiles/block =====
// r10: clone of gemm2's (empirically 437 ns/phase) ITER structure.
// 8 waves 4Mx2N, per-wave 64x64, acc[4][4]. LDS 112 KiB:
// A0@0, A1@16384 (32 KB each), B bufs @32768/40960/49152 (16 KB each, ushorts).
// Persistent: j = 0..7, nt = ntb + 6j; continuous pipeline, uniform ITER
// (garbage-wrap tail); boundary epilogue in dead bC_ (2 chunks x 128 rows).
template<int KD>
__global__ __launch_bounds__(512, 2) void gemm1_4ph(
    const unsigned short* __restrict__ A,
    const unsigned short* __restrict__ Bw,
    unsigned short* __restrict__ H) {
  __shared__ unsigned short lds[57344];
  constexpr size_t JSTR = (size_t)6*128*KD;      // nt += 6 stride (128-row tiles)

  const int bid = blockIdx.x;
  const int chunk = gridDim.x >> 3;              // 240/8 = 30 (one expert/XCD)
  const int tile = (bid & 7)*chunk + (bid >> 3);
  const int e = tile / 30;
  const int r30 = tile % 30;
  const int ntb = r30 / 5, mt = r30 % 5;

  const int tid = threadIdx.x;
  const int l = tid & 63, wid = tid >> 6;
  const int wr = wid >> 1, wc = wid & 1;
  const int lrow = l & 15, khi = l >> 4;

  const unsigned short* Ab = A  + (size_t)e*CAP*KD      + (size_t)mt*256*KD;
  const unsigned short* Bb = Bw + (size_t)e*(2*IDIM)*KD + (size_t)ntb*128*KD;

  const int srow = tid >> 3;
  const int scol = (tid & 7) ^ (srow & 7);
  const size_t lane_off = (size_t)srow*KD + scol*8;
  const int lds_st = wid*512;

#define STG(dstu, srcp, half, kt) do { \
    const unsigned short* s_ = (srcp) + lane_off + (size_t)(half)*128*KD + (size_t)(kt)*64; \
    unsigned short* d_ = (unsigned short*)lds + (dstu) + (half)*8192 + lds_st; \
    __builtin_amdgcn_global_load_lds((const __attribute__((address_space(1))) void*)s_, \
        (__attribute__((address_space(3))) void*)d_, 16, 0, 0); \
    __builtin_amdgcn_global_load_lds((const __attribute__((address_space(1))) void*)(s_ + (size_t)64*KD), \
        (__attribute__((address_space(3))) void*)(d_ + 4096), 16, 0, 0); \
  } while(0)

  const int swz0 = ((khi    ) ^ (lrow & 7)) * 8;
  const int swz1 = ((4 + khi) ^ (lrow & 7)) * 8;
  const int aoff = wr*4096 + lrow*64;            // A rows: wr*64 + m*16 + lrow
  const int boff = wc*4096 + lrow*64;            // B rows: wc*64 + n*16 + lrow

#define LDA(ab, dst) do { _Pragma("unroll") for (int m_=0;m_<4;++m_) { \
    dst[m_][0] = *(const short8*)(lds + (ab) + aoff + m_*1024 + swz0); \
    dst[m_][1] = *(const short8*)(lds + (ab) + aoff + m_*1024 + swz1); } } while(0)
#define LDB(bb, dst, nb) do { _Pragma("unroll") for (int n_=0;n_<2;++n_) { \
    dst[n_][0] = *(const short8*)(lds + (bb) + boff + ((nb)+n_)*1024 + swz0); \
    dst[n_][1] = *(const short8*)(lds + (bb) + boff + ((nb)+n_)*1024 + swz1); } } while(0)
#define QUAD(af, bf, nb) do { _Pragma("unroll") for (int r_=0;r_<2;++r_) \
    _Pragma("unroll") for (int n_=0;n_<2;++n_) \
    _Pragma("unroll") for (int m_=0;m_<4;++m_) \
      acc[m_][(nb)+n_] = __builtin_amdgcn_mfma_f32_16x16x32_bf16(af[m_][r_], bf[n_][r_], acc[m_][(nb)+n_], 0,0,0); } while(0)

  f32x4 acc[4][4];
#pragma unroll
  for (int i = 0; i < 4; ++i)
#pragma unroll
    for (int j = 0; j < 4; ++j) acc[i][j] = (f32x4){0.f,0.f,0.f,0.f};

  short8 a[4][2], bl[2][2], bh[2][2];

  int bA_ = 32768, bB_ = 40960, bC_ = 49152;

  // prologue: kappa=0 {A0 4 loads, bA_ 2}, kappa=1 {A1 4, bB_ 2}; VMW(6)
  // retires kappa0's 6; enter steady state with 6 in flight (kappa1's).
  STG(0, Ab, 0, 0); STG(0, Ab, 1, 0); STG(bA_, Bb, 0, 0);
  STG(16384, Ab, 0, 1); STG(16384, Ab, 1, 1); STG(bB_, Bb, 0, 1);
  VMW(6);
  BAR;

  // uniform ITER: computes kappa (A0,bA_), kappa+1 (A1,bB_); stages kappa+2
  // {B->bC_ ph1 (2), A->A0 ph2 (4)} and kappa+3 {B->bA_ ph3 (2), A->A1 ph4 (4)}.
  // VMW(6) at ph2 retires kappa+1 (guards ph3 reads); VMW(6) at ph4 retires
  // kappa+2 (guards next ITER's ph1 reads). 12 issue / 12 retire per ITER.
#define ITER(k2p, B2) \
    LDA(0, a); LDB(bA_, bl, 0); STG(bC_, (B2), 0, (k2p)); \
    BAR; P1; QUAD(a, bl, 0); P0; BAR; \
    LDB(bA_, bh, 2); STG(0, Ab, 0, (k2p)); STG(0, Ab, 1, (k2p)); VMW(6); \
    BAR; P1; QUAD(a, bh, 2); P0; BAR; \
    LDA(16384, a); LDB(bB_, bl, 0); STG(bA_, (B2), 0, (k2p)+1); \
    BAR; P1; QUAD(a, bl, 0); P0; BAR; \
    LDB(bB_, bh, 2); STG(16384, Ab, 0, (k2p)+1); STG(16384, Ab, 1, (k2p)+1); VMW(6); \
    BAR; P1; QUAD(a, bh, 2); P0; BAR;

  const size_t rowg = (size_t)e*CAP + (size_t)mt*256;
  int itr = 0;

#pragma unroll 1
  for (int j = 0; j < 8; ++j) {
#pragma unroll 1
    for (int ii = 0; ii < 6; ++ii) {
      int t2 = 2*itr + 2;
      if (t2 >= 96) t2 = 0;                      // tail wrap (garbage stage)
      int j2 = t2 / 12, k2 = t2 - j2*12;         // t2 even -> k2,k2+1 same j
      const unsigned short* B2 = Bb + (size_t)j2*JSTR;
      ITER(k2, B2);
      int tmp = bC_; bC_ = bB_; bB_ = bA_; bA_ = tmp;
      ++itr;
    }
    // ---- boundary epilogue for tile j in dead region bC_ (post-rotation) ---
    // dead: new bC_ = old bB_ (kappa+1's B, consumed; no in-flight writes).
    // 2 chunks of 128 rows; LDS layout [128][64] us (16 KB exactly).
    {
      const size_t ntcol = (size_t)(ntb + 6*j)*64;   // H cols (128 comb -> 64)
#pragma unroll
      for (int c = 0; c < 2; ++c) {
        BAR;                                    // prev chunk reads done
        if ((wr >> 1) == c) {
#pragma unroll
          for (int m_ = 0; m_ < 4; ++m_) {
#pragma unroll
            for (int p = 0; p < 2; ++p) {
              f32x4 g = acc[m_][2*p], u = acc[m_][2*p+1];
#pragma unroll
              for (int r = 0; r < 4; ++r) {
                float gv = g[r];
                float hv = gv / (1.f + __expf(-gv)) * u[r];
                int rrel = (wr & 1)*64 + m_*16 + khi*4 + r;
                lds[bC_ + rrel*64 + (2*wc + p)*16 + lrow] = f2b(hv);
              }
            }
          }
        }
        LGW;                                    // ds_writes visible
        BAR;
#pragma unroll
        for (int q = 0; q < 2; ++q) {
          int idx = tid + 512*q;                // 0..1023
          int rp = idx >> 3, ch = idx & 7;      // 128 rows x 8 chunks
          us8 v = *(const us8*)(lds + bC_ + rp*64 + ch*8);
          *(us8*)(H + (rowg + 128*c + rp)*(size_t)IDIM + ntcol + ch*8) = v;
        }
      }
      BAR;   // protect bC_ before next ITER's ph1 STG into it
    }
#pragma unroll
    for (int i2 = 0; i2 < 4; ++i2)
#pragma unroll
      for (int j2 = 0; j2 < 4; ++j2) acc[i2][j2] = (f32x4){0.f,0.f,0.f,0.f};
  }

#undef ITER
#undef QUAD
#undef LDB
#undef LDA
#undef STG
}

// =============== GEMM2: 256x128 8-phase deep pipeline (K=3072, 24 ITERs) =====
template<int KD>
__global__ __launch_bounds__(512, 2) void gemm2_8ph(
    const unsigned short* __restrict__ A,
    const unsigned short* __restrict__ Bw,
    unsigned short* __restrict__ O) {
  constexpr int NT = KD/64;        // 48
  constexpr int NITER = NT/2;      // 24
  __shared__ unsigned short lds[57344];

  const int bid = blockIdx.x;
  const int chunk = gridDim.x >> 3;              // 30
  const int tile = (bid & 7)*chunk + (bid >> 3);
  const int e = tile / 30;
  const int rem = tile % 30;
  const int nt = rem / 5, mt = rem % 5;

  const int tid = threadIdx.x;
  const int l = tid & 63, wid = tid >> 6;
  const int wr = wid >> 1, wc = wid & 1;
  const int lrow = l & 15, khi = l >> 4;

  const unsigned short* Ab = A  + (size_t)e*CAP*KD  + (size_t)mt*256*KD;
  const unsigned short* Bb = Bw + (size_t)e*CDIM*KD + (size_t)nt*128*KD;

  const int srow = tid >> 3;
  const int scol = (tid & 7) ^ (srow & 7);
  const size_t lane_off = (size_t)srow*KD + scol*8;
  const int lds_st = wid*512;

#define STG(dstu, srcp, half, kt) do { \
    const unsigned short* s_ = (srcp) + lane_off + (size_t)(half)*128*KD + (size_t)(kt)*64; \
    unsigned short* d_ = (unsigned short*)lds + (dstu) + (half)*8192 + lds_st; \
    __builtin_amdgcn_global_load_lds((const __attribute__((address_space(1))) void*)s_, \
        (__attribute__((address_space(3))) void*)d_, 16, 0, 0); \
    __builtin_amdgcn_global_load_lds((const __attribute__((address_space(1))) void*)(s_ + (size_t)64*KD), \
        (__attribute__((address_space(3))) void*)(d_ + 4096), 16, 0, 0); \
  } while(0)

  const int swz0 = ((khi    ) ^ (lrow & 7)) * 8;
  const int swz1 = ((4 + khi) ^ (lrow & 7)) * 8;
  const int aoff = wr*4096 + lrow*64;
  const int boff = wc*4096 + lrow*64;

#define LDA(ab, dst) do { _Pragma("unroll") for (int m_=0;m_<4;++m_) { \
    dst[m_][0] = *(const short8*)(lds + (ab) + aoff + m_*1024 + swz0); \
    dst[m_][1] = *(const short8*)(lds + (ab) + aoff + m_*1024 + swz1); } } while(0)
#define LDB(bb, dst, nb) do { _Pragma("unroll") for (int n_=0;n_<2;++n_) { \
    dst[n_][0] = *(const short8*)(lds + (bb) + boff + ((nb)+n_)*1024 + swz0); \
    dst[n_][1] = *(const short8*)(lds + (bb) + boff + ((nb)+n_)*1024 + swz1); } } while(0)
#define QUAD(af, bf, nb) do { _Pragma("unroll") for (int r_=0;r_<2;++r_) \
    _Pragma("unroll") for (int n_=0;n_<2;++n_) \
    _Pragma("unroll") for (int m_=0;m_<4;++m_) \
      acc[m_][(nb)+n_] = __builtin_amdgcn_mfma_f32_16x16x32_bf16(af[m_][r_], bf[n_][r_], acc[m_][(nb)+n_], 0,0,0); } while(0)

  f32x4 acc[4][4];
#pragma unroll
  for (int i = 0; i < 4; ++i)
#pragma unroll
    for (int j = 0; j < 4; ++j) acc[i][j] = (f32x4){0.f,0.f,0.f,0.f};

  short8 a[4][2], bl[2][2], bh[2][2];

  int bA_ = 32768, bB_ = 40960, bC_ = 49152;

  STG(0, Ab, 0, 0); STG(0, Ab, 1, 0); STG(bA_, Bb, 0, 0);
  STG(16384, Ab, 0, 1); STG(16384, Ab, 1, 1); STG(bB_, Bb, 0, 1);
  VMW(6);
  BAR;

#define ITER2(t2, t3, DOS, VM2, VM4) \
    LDA(0, a); LDB(bA_, bl, 0); if (DOS) STG(bC_, Bb, 0, (t2)); \
    BAR; P1; QUAD(a, bl, 0); P0; BAR; \
    LDB(bA_, bh, 2); if (DOS) { STG(0, Ab, 0, (t2)); STG(0, Ab, 1, (t2)); } VM2; \
    BAR; P1; QUAD(a, bh, 2); P0; BAR; \
    LDA(16384, a); LDB(bB_, bl, 0); if (DOS) STG(bA_, Bb, 0, (t3)); \
    BAR; P1; QUAD(a, bl, 0); P0; BAR; \
    LDB(bB_, bh, 2); if (DOS) { STG(16384, Ab, 0, (t3)); STG(16384, Ab, 1, (t3)); } VM4; \
    BAR; P1; QUAD(a, bh, 2); P0; BAR;

#pragma unroll 1
  for (int i = 0; i < NITER-1; ++i) {
    const int t2 = 2*i+2, t3 = 2*i+3;
    ITER2(t2, t3, true, VMW(6), VMW(6));
    int tmp = bC_; bC_ = bB_; bB_ = bA_; bA_ = tmp;
  }
  ITER2(0, 0, false, VMW(0), VMW(0));

#undef ITER2
#undef QUAD
#undef LDB
#undef LDA
#undef STG

  __syncthreads();
  {
    const int cb0 = wc*64 + lrow;
    const int rb0 = wr*64 + khi*4;
#pragma unroll
    for (int m = 0; m < 4; ++m)
#pragma unroll
      for (int n = 0; n < 4; ++n) {
        f32x4 v = acc[m][n];
#pragma unroll
        for (int r = 0; r < 4; ++r)
          lds[(rb0 + m*16 + r)*136 + cb0 + n*16] = f2b(v[r]);
      }
  }
  __syncthreads();
  const size_t rowg = (size_t)e*CAP + (size_t)mt*256;
  const size_t colg = (size_t)nt*128 + (size_t)(l & 15)*8;
#pragma unroll
  for (int i = 0; i < 8; ++i) {
    int row = wid*32 + i*4 + (l >> 4);
    us8 v = *(const us8*)(lds + row*136 + (l & 15)*8);
    *(us8*)(O + (rowg + row)*(size_t)CDIM + colg) = v;
  }
}

// ---------------- combine (bf16 expert outputs -> f32 y) ----------------
__global__ __launch_bounds__(192) void combine_kernel(const unsigned short* __restrict__ outbuf,
    const int* __restrict__ c1, const int* __restrict__ c2,
    const float* __restrict__ g1, const float* __restrict__ g2,
    float* __restrict__ y) {
  int t = blockIdx.x;
  int q = threadIdx.x;
  float f1 = g1[t], f2 = g2[t];
  int a = c1[t], b = c2[t];
  us4 va = ((const us4*)outbuf)[(size_t)a*(CDIM/4) + q];
  us4 vb = ((const us4*)outbuf)[(size_t)b*(CDIM/4) + q];
  float4 r;
  r.x = f1*b2f(va.x) + f2*b2f(vb.x);
  r.y = f1*b2f(va.y) + f2*b2f(vb.y);
  r.z = f1*b2f(va.z) + f2*b2f(vb.z);
  r.w = f1*b2f(va.w) + f2*b2f(vb.w);
  ((float4*)y)[(size_t)t*(CDIM/4) + q] = r;
}

extern "C" void kernel_launch(void* const* d_in, const int* in_sizes, int n_in,
                              void* d_out, int out_size, void* d_ws, size_t ws_size,
                              hipStream_t stream) {
  const float* x  = (const float*)d_in[0];
  const float* Wr = (const float*)d_in[1];
  const float* Wg = (const float*)d_in[2];
  const float* Wu = (const float*)d_in[3];
  const float* Wp = (const float*)d_in[4];
  float* y = (float*)d_out;

  char* p = (char*)d_ws;
  auto alloc = [&](size_t bytes) { char* r = p; p += (bytes + 255) & ~(size_t)255; return r; };
  unsigned short* WguT = (unsigned short*)alloc((size_t)NEXP*2*IDIM*CDIM*2);
  unsigned short* WpT  = (unsigned short*)alloc((size_t)NEXP*CDIM*IDIM*2);
  unsigned short* ein  = (unsigned short*)alloc((size_t)EROWS*CDIM*2);
  unsigned short* h    = (unsigned short*)alloc((size_t)EROWS*IDIM*2);
  unsigned short* outbuf = (unsigned short*)alloc((size_t)EROWS*CDIM*2);
  float* probs  = (float*)alloc((size_t)NTOK*NEXP*4);
  int* idx1 = (int*)alloc(NTOK*4);
  int* idx2 = (int*)alloc(NTOK*4);
  int* c1   = (int*)alloc(NTOK*4);
  int* c2   = (int*)alloc(NTOK*4);
  float* g1r = (float*)alloc(NTOK*4);
  float* g2r = (float*)alloc(NTOK*4);
  float* g1o = (float*)alloc(NTOK*4);
  float* g2o = (float*)alloc(NTOK*4);
  int* bufmap = (int*)alloc(EROWS*4);

  size_t required = (size_t)(p - (char*)d_ws);
  if (ws_size < required) return;

  hipMemsetAsync(bufmap, 0xFF, EROWS*sizeof(int), stream);

  wgu_cvt64<<<2*NEXP*(CDIM/64)*(IDIM/64), 256, 0, stream>>>(Wg, Wu, WguT);
  transpose_cvt64<<<NEXP*(IDIM/64)*(CDIM/64), 256, 0, stream>>>(Wp, WpT, IDIM, CDIM);

  router_kernel<<<NTOK/4, 256, 0, stream>>>(x, Wr, probs, idx1, idx2, g1r, g2r);
  scan_kernel<<<1, 1024, 0, stream>>>(idx1, idx2, g1r, g2r, probs, bufmap,
                                      c1, c2, g1o, g2o, y + (size_t)NTOK*CDIM);
  dispatch_kernel<<<EROWS, 192, 0, stream>>>(x, bufmap, ein);

  gemm1_4ph<CDIM><<<240, 512, 0, stream>>>(ein, WguT, h);
  gemm2_8ph<IDIM><<<NEXP*5*(CDIM/128), 512, 0, stream>>>(h, WpT, outbuf);

  combine_kernel<<<NTOK, 192, 0, stream>>>(outbuf, c1, c2, g1o, g2o, y);
}

// Round 11
// 284.909 us; speedup vs baseline: 1.0803x; 1.0803x over previous
//
#include <hip/hip_runtime.h>
#include <cstdint>
#include <cstddef>

#define NTOK 8192
#define NEXP 8
#define CAP 1280
#define CDIM 768
#define IDIM 3072
#define EROWS (NEXP*CAP)   /* 10240 */

typedef __attribute__((ext_vector_type(8))) short short8;
typedef __attribute__((ext_vector_type(4))) float f32x4;
typedef __attribute__((ext_vector_type(4))) unsigned short us4;
typedef __attribute__((ext_vector_type(8))) unsigned short us8;

__device__ __forceinline__ unsigned short f2b(float f) {
  unsigned u = __builtin_bit_cast(unsigned, f);
  u += 0x7FFFu + ((u >> 16) & 1u);          // round-to-nearest-even
  return (unsigned short)(u >> 16);
}
__device__ __forceinline__ float b2f(unsigned short u) {
  return __builtin_bit_cast(float, ((unsigned)u) << 16);
}

// ======= fused weight prep: Wg+Wu -> interleaved Wgu^T bf16; Wp -> WpT bf16 ==
// branch is uniform per block (blockIdx-based), 64x64 f32 tile, +1 pad.
__global__ __launch_bounds__(256) void weights_cvt(
    const float* __restrict__ Wg, const float* __restrict__ Wu,
    const float* __restrict__ Wp,
    unsigned short* __restrict__ Wgu, unsigned short* __restrict__ WpT) {
  __shared__ float tile[64][65];
  const int perEgu = (CDIM/64)*(IDIM/64);        // 576
  const int NWGU = 2*NEXP*perEgu;                // 9216
  int c4 = (threadIdx.x & 15)*4, rr = threadIdx.x >> 4;
  int bid = blockIdx.x;
  if (bid < NWGU) {
    int sel = bid / (NEXP*perEgu);
    int rem = bid % (NEXP*perEgu);
    int e = rem / perEgu; int r2 = rem % perEgu;
    int rt = r2 / (IDIM/64), st = r2 % (IDIM/64);
    const float* se = (sel ? Wu : Wg) + (size_t)e*CDIM*IDIM + ((size_t)rt*64)*IDIM + st*64;
#pragma unroll
    for (int p = 0; p < 4; ++p) {
      float4 v = *(const float4*)(se + (size_t)(rr + 16*p)*IDIM + c4);
      tile[rr + 16*p][c4+0] = v.x; tile[rr + 16*p][c4+1] = v.y;
      tile[rr + 16*p][c4+2] = v.z; tile[rr + 16*p][c4+3] = v.w;
    }
    __syncthreads();
    unsigned short* dstE = Wgu + (size_t)e*(2*IDIM)*CDIM;
#pragma unroll
    for (int p = 0; p < 4; ++p) {
      int s = rr + 16*p;
      int np = 128*st + 32*(s>>4) + (s&15) + sel*16;
      us4 o;
      o.x = f2b(tile[c4+0][s]); o.y = f2b(tile[c4+1][s]);
      o.z = f2b(tile[c4+2][s]); o.w = f2b(tile[c4+3][s]);
      *(us4*)(dstE + (size_t)np*CDIM + rt*64 + c4) = o;
    }
  } else {
    bid -= NWGU;
    const int tilesS = CDIM/64;                  // 12 (R=IDIM, S=CDIM)
    const int perE = (IDIM/64)*tilesS;           // 576
    int e = bid / perE, rem2 = bid % perE;
    int rt = rem2 / tilesS, st = rem2 % tilesS;
    const float* se = Wp + (size_t)e*IDIM*CDIM + ((size_t)rt*64)*CDIM + st*64;
    unsigned short* de = WpT + (size_t)e*IDIM*CDIM + ((size_t)st*64)*IDIM + rt*64;
#pragma unroll
    for (int p = 0; p < 4; ++p) {
      float4 v = *(const float4*)(se + (size_t)(rr + 16*p)*CDIM + c4);
      tile[rr + 16*p][c4+0] = v.x; tile[rr + 16*p][c4+1] = v.y;
      tile[rr + 16*p][c4+2] = v.z; tile[rr + 16*p][c4+3] = v.w;
    }
    __syncthreads();
#pragma unroll
    for (int p = 0; p < 4; ++p) {
      int s = rr + 16*p;
      us4 o;
      o.x = f2b(tile[c4+0][s]); o.y = f2b(tile[c4+1][s]);
      o.z = f2b(tile[c4+2][s]); o.w = f2b(tile[c4+3][s]);
      *(us4*)(de + (size_t)s*IDIM + c4) = o;
    }
  }
}

// ---------------- router ----------------
__global__ __launch_bounds__(256) void router_kernel(const float* __restrict__ x,
    const float* __restrict__ Wr, float* __restrict__ probs,
    int* __restrict__ idx1, int* __restrict__ idx2,
    float* __restrict__ g1r, float* __restrict__ g2r) {
  __shared__ float WrT[NEXP*CDIM];
  for (int i = threadIdx.x; i < NEXP*CDIM; i += 256) {
    int c = i >> 3, e = i & 7;
    WrT[e*CDIM + c] = Wr[i];
  }
  __syncthreads();
  int w = threadIdx.x >> 6, l = threadIdx.x & 63;
  int t = blockIdx.x*4 + w;
  float acc[NEXP];
#pragma unroll
  for (int e = 0; e < NEXP; ++e) acc[e] = 0.f;
  for (int k = 0; k < CDIM/64; ++k) {
    float xv = x[(size_t)t*CDIM + k*64 + l];
#pragma unroll
    for (int e = 0; e < NEXP; ++e) acc[e] += xv * WrT[e*CDIM + k*64 + l];
  }
#pragma unroll
  for (int off = 32; off > 0; off >>= 1) {
#pragma unroll
    for (int e = 0; e < NEXP; ++e) acc[e] += __shfl_xor(acc[e], off);
  }
  if (l == 0) {
    float m = acc[0];
#pragma unroll
    for (int e = 1; e < NEXP; ++e) m = fmaxf(m, acc[e]);
    float p[NEXP]; float s = 0.f;
#pragma unroll
    for (int e = 0; e < NEXP; ++e) { p[e] = expf(acc[e] - m); s += p[e]; }
    float inv = 1.f / s;
#pragma unroll
    for (int e = 0; e < NEXP; ++e) { p[e] *= inv; probs[(size_t)t*NEXP + e] = p[e]; }
    int i1 = 0; float b1 = p[0];
#pragma unroll
    for (int e = 1; e < NEXP; ++e) if (p[e] > b1) { b1 = p[e]; i1 = e; }
    int i2 = -1; float b2 = -1e30f;
#pragma unroll
    for (int e = 0; e < NEXP; ++e) if (e != i1 && p[e] > b2) { b2 = p[e]; i2 = e; }
    float gs = fmaxf(b1 + b2, 1e-9f);
    g1r[t] = b1 / gs; g2r[t] = b2 / gs;
    idx1[t] = i1; idx2[t] = i2;
  }
}

// ---------------- scan (now also initializes bufmap to -1) ----------------
__global__ __launch_bounds__(1024) void scan_kernel(
    const int* __restrict__ idx1, const int* __restrict__ idx2,
    const float* __restrict__ g1r, const float* __restrict__ g2r,
    const float* __restrict__ probs,
    int* __restrict__ bufmap,
    int* __restrict__ c1o, int* __restrict__ c2o,
    float* __restrict__ g1o, float* __restrict__ g2o,
    float* __restrict__ aux_out) {
  __shared__ unsigned int scanbuf[1024][9];
  __shared__ unsigned int totals[NEXP];
  int tid = threadIdx.x;
  for (int i = tid; i < EROWS; i += 1024) bufmap[i] = -1;   // ordered before
                                                            // claims by the
                                                            // scan barriers
  int e1[8], e2[8];
  unsigned int cnt[NEXP];
#pragma unroll
  for (int k = 0; k < NEXP; ++k) cnt[k] = 0;
  for (int j = 0; j < 8; ++j) {
    int t = tid*8 + j;
    e1[j] = idx1[t]; e2[j] = idx2[t];
    cnt[e1[j]] += 1u;
    cnt[e2[j]] += (1u << 16);
  }
#pragma unroll
  for (int k = 0; k < NEXP; ++k) scanbuf[tid][k] = cnt[k];
  unsigned int run[NEXP];
#pragma unroll
  for (int k = 0; k < NEXP; ++k) run[k] = cnt[k];
  __syncthreads();
  for (int off = 1; off < 1024; off <<= 1) {
    unsigned int add[NEXP];
#pragma unroll
    for (int k = 0; k < NEXP; ++k) add[k] = 0;
    if (tid >= off) {
#pragma unroll
      for (int k = 0; k < NEXP; ++k) add[k] = scanbuf[tid - off][k];
    }
    __syncthreads();
#pragma unroll
    for (int k = 0; k < NEXP; ++k) { run[k] += add[k]; scanbuf[tid][k] = run[k]; }
    __syncthreads();
  }
  if (tid == 1023) {
#pragma unroll
    for (int k = 0; k < NEXP; ++k) totals[k] = run[k];
  }
  __syncthreads();
  unsigned int excl[NEXP];
#pragma unroll
  for (int k = 0; k < NEXP; ++k) excl[k] = run[k] - cnt[k];
  int cnt1c[NEXP];
#pragma unroll
  for (int k = 0; k < NEXP; ++k) cnt1c[k] = min((int)(totals[k] & 0xFFFFu), CAP);

  for (int j = 0; j < 8; ++j) {
    int t = tid*8 + j;
    int a = e1[j];
    int pos1 = (int)(excl[a] & 0xFFFFu); excl[a] += 1u;
    int slot1 = a*CAP + pos1;
    bool m1 = pos1 < CAP;
    if (m1) bufmap[slot1] = t;
    int b = e2[j];
    int pos2 = (int)(excl[b] >> 16) + cnt1c[b]; excl[b] += (1u << 16);
    int slot2 = b*CAP + pos2;
    bool m2 = pos2 < CAP;
    if (m2) bufmap[slot2] = t;
    float G1 = m1 ? g1r[t] : 0.f;
    float G2 = m2 ? g2r[t] : 0.f;
    float den = fmaxf(G1 + G2, 1e-9f);
    g1o[t] = G1 / den; g2o[t] = G2 / den;
    c1o[t] = min(slot1, EROWS - 1);
    c2o[t] = min(slot2, EROWS - 1);
  }

  float imp[NEXP];
#pragma unroll
  for (int k = 0; k < NEXP; ++k) imp[k] = 0.f;
  for (int j = 0; j < 8; ++j) {
    int t = tid*8 + j;
    const float4* pr = (const float4*)(probs + (size_t)t*NEXP);
    float4 a0 = pr[0], a1 = pr[1];
    imp[0] += a0.x; imp[1] += a0.y; imp[2] += a0.z; imp[3] += a0.w;
    imp[4] += a1.x; imp[5] += a1.y; imp[6] += a1.z; imp[7] += a1.w;
  }
  __syncthreads();
  float* fbuf = (float*)&scanbuf[0][0];
#pragma unroll
  for (int k = 0; k < NEXP; ++k) fbuf[tid*9 + k] = imp[k];
  __syncthreads();
  for (int s = 512; s >= 1; s >>= 1) {
    if (tid < s) {
#pragma unroll
      for (int k = 0; k < NEXP; ++k) fbuf[tid*9 + k] += fbuf[(tid + s)*9 + k];
    }
    __syncthreads();
  }
  if (tid == 0) {
    float aux = 0.f;
#pragma unroll
    for (int k = 0; k < NEXP; ++k) {
      float importance = fbuf[k] / (float)NTOK;
      float loadk = (float)((totals[k] & 0xFFFFu) + (totals[k] >> 16)) / ((float)NTOK * 2.0f);
      aux += importance * loadk;
    }
    aux_out[0] = aux * (float)NEXP * 0.01f;
  }
}

// ---------------- dispatch: grid-stride gather x -> ein (bf16) ----------------
__global__ __launch_bounds__(256) void dispatch_kernel(const float* __restrict__ x,
    const int* __restrict__ bufmap, unsigned short* __restrict__ ein) {
  const int TOT = EROWS*(CDIM/4);
  for (int idx = blockIdx.x*256 + threadIdx.x; idx < TOT; idx += gridDim.x*256) {
    int r = idx / (CDIM/4), q = idx - r*(CDIM/4);
    int t = bufmap[r];
    float4 v = make_float4(0.f, 0.f, 0.f, 0.f);
    if (t >= 0) v = ((const float4*)x)[(size_t)t*(CDIM/4) + q];
    us4 o;
    o.x = f2b(v.x); o.y = f2b(v.y); o.z = f2b(v.z); o.w = f2b(v.w);
    ((us4*)ein)[(size_t)r*(CDIM/4) + q] = o;
  }
}

#define BAR  asm volatile("s_barrier" ::: "memory")
#define VMW(N) asm volatile("s_waitcnt vmcnt(" #N ")" ::: "memory")
#define LGW  asm volatile("s_waitcnt lgkmcnt(0)" ::: "memory")
#define P1 __builtin_amdgcn_s_setprio(1)
#define P0 __builtin_amdgcn_s_setprio(0)

// =============== GEMM1: persistent 256x256 8-phase (r9, verified 117us) ======
template<int KD>
__global__ __launch_bounds__(512, 2) void gemm1_8ph(
    const unsigned short* __restrict__ A,
    const unsigned short* __restrict__ Bw,
    unsigned short* __restrict__ H) {
  __shared__ unsigned short lds[81920];
  constexpr size_t JSTR = (size_t)6*256*KD;

  const int bid = blockIdx.x;
  const int chunk = gridDim.x >> 3;
  const int tile = (bid & 7)*chunk + (bid >> 3);
  const int e = tile / 30;
  const int r30 = tile % 30;
  const int ntb = r30 / 5, mt = r30 % 5;

  const int tid = threadIdx.x;
  const int l = tid & 63, wid = tid >> 6;
  const int wr = wid >> 2, wc = wid & 3;
  const int lrow = l & 15, khi = l >> 4;

  const unsigned short* Ab = A  + (size_t)e*CAP*KD      + (size_t)mt*256*KD;
  const unsigned short* Bb = Bw + (size_t)e*(2*IDIM)*KD + (size_t)ntb*256*KD;

  const int srow = tid >> 3;
  const int scol = (tid & 7) ^ (srow & 7);
  const size_t lane_off = (size_t)srow*KD + scol*8;
  const int lds_st = wid*512;

#define STG(dstu, srcp, half, kt) do { \
    const unsigned short* s_ = (srcp) + lane_off + (size_t)(half)*128*KD + (size_t)(kt)*64; \
    unsigned short* d_ = (unsigned short*)lds + (dstu) + (half)*8192 + lds_st; \
    __builtin_amdgcn_global_load_lds((const __attribute__((address_space(1))) void*)s_, \
        (__attribute__((address_space(3))) void*)d_, 16, 0, 0); \
    __builtin_amdgcn_global_load_lds((const __attribute__((address_space(1))) void*)(s_ + (size_t)64*KD), \
        (__attribute__((address_space(3))) void*)(d_ + 4096), 16, 0, 0); \
  } while(0)

  const int swz0 = ((khi    ) ^ (lrow & 7)) * 8;
  const int swz1 = ((4 + khi) ^ (lrow & 7)) * 8;
  const int aoff = wr*8192 + lrow*64;
  const int boff = (wc>>1)*8192 + ((wc&1)*64 + lrow)*64;

#define LDA(ab, dst, mb) do { _Pragma("unroll") for (int m_=0;m_<4;++m_) { \
    dst[m_][0] = *(const short8*)(lds + (ab) + aoff + ((mb)+m_)*1024 + swz0); \
    dst[m_][1] = *(const short8*)(lds + (ab) + aoff + ((mb)+m_)*1024 + swz1); } } while(0)
#define LDB(bb, dst, nb) do { _Pragma("unroll") for (int n_=0;n_<2;++n_) { \
    dst[n_][0] = *(const short8*)(lds + (bb) + boff + ((nb)+n_)*1024 + swz0); \
    dst[n_][1] = *(const short8*)(lds + (bb) + boff + ((nb)+n_)*1024 + swz1); } } while(0)
#define QUAD(af, bf, mb, nb) do { _Pragma("unroll") for (int r_=0;r_<2;++r_) \
    _Pragma("unroll") for (int n_=0;n_<2;++n_) \
    _Pragma("unroll") for (int m_=0;m_<4;++m_) \
      acc[(mb)+m_][(nb)+n_] = __builtin_amdgcn_mfma_f32_16x16x32_bf16(af[m_][r_], bf[n_][r_], acc[(mb)+m_][(nb)+n_], 0,0,0); } while(0)

  f32x4 acc[8][4];
#pragma unroll
  for (int i = 0; i < 8; ++i)
#pragma unroll
    for (int j = 0; j < 4; ++j) acc[i][j] = (f32x4){0.f,0.f,0.f,0.f};

  short8 a[4][2], bl[2][2], bh[2][2];

  int bA_ = 32768, bB_ = 49152, bC_ = 65536;

  STG(0, Ab, 0, 0);      STG(bA_, Bb, 0, 0);
  STG(0, Ab, 1, 0);      STG(bA_, Bb, 1, 0);
  STG(16384, Ab, 0, 1);  STG(bB_, Bb, 0, 1);
  STG(16384, Ab, 1, 1);  STG(bB_, Bb, 1, 1);
  VMW(8);
  BAR;

#define ITER(k2p, B2) \
    LDA(0, a, 0); LDB(bA_, bl, 0); STG(bC_, (B2), 0, (k2p)); \
    BAR; P1; QUAD(a, bl, 0, 0); P0; BAR; \
    LDB(bA_, bh, 2); STG(bC_, (B2), 1, (k2p)); \
    BAR; P1; QUAD(a, bh, 0, 2); P0; BAR; \
    LDA(0, a, 4); \
    BAR; P1; QUAD(a, bh, 4, 2); P0; BAR; \
    STG(0, Ab, 0, (k2p)); VMW(6); \
    BAR; P1; QUAD(a, bl, 4, 0); P0; BAR; \
    LDA(16384, a, 0); LDB(bB_, bl, 0); STG(0, Ab, 1, (k2p)); STG(bA_, (B2), 0, (k2p)+1); \
    BAR; P1; QUAD(a, bl, 0, 0); P0; BAR; \
    LDB(bB_, bh, 2); STG(bA_, (B2), 1, (k2p)+1); \
    BAR; P1; QUAD(a, bh, 0, 2); P0; BAR; \
    LDA(16384, a, 4); \
    BAR; P1; QUAD(a, bh, 4, 2); P0; BAR; \
    STG(16384, Ab, 0, (k2p)+1); STG(16384, Ab, 1, (k2p)+1); VMW(8); \
    BAR; P1; QUAD(a, bl, 4, 0); P0; BAR;

  const size_t rowg = (size_t)e*CAP + (size_t)mt*256;
  int itr = 0;

#pragma unroll 1
  for (int j = 0; j < 4; ++j) {
#pragma unroll 1
    for (int ii = 0; ii < 6; ++ii) {
      int t2 = 2*itr + 2;
      if (t2 >= 48) t2 = 0;                      // tail wrap (garbage stage)
      int j2 = t2 / 12, k2 = t2 - j2*12;
      const unsigned short* B2 = Bb + (size_t)j2*JSTR;
      ITER(k2, B2);
      int tmp = bC_; bC_ = bB_; bB_ = bA_; bA_ = tmp;
      ++itr;
    }
    {
      const size_t ntcol = (size_t)(ntb + 6*j)*128;
#pragma unroll
      for (int c = 0; c < 4; ++c) {
        BAR;
        if (wr == (c >> 1)) {
#pragma unroll
          for (int m_ = 0; m_ < 4; ++m_) {
#pragma unroll
            for (int p = 0; p < 2; ++p) {
              f32x4 g = acc[(c & 1)*4 + m_][2*p], u = acc[(c & 1)*4 + m_][2*p+1];
#pragma unroll
              for (int r = 0; r < 4; ++r) {
                float gv = g[r];
                float hv = gv / (1.f + __expf(-gv)) * u[r];
                lds[bC_ + (m_*16 + khi*4 + r)*136 + wc*32 + lrow + p*16] = f2b(hv);
              }
            }
          }
        }
        LGW;
        BAR;
#pragma unroll
        for (int q = 0; q < 2; ++q) {
          int idx = tid + 512*q;
          int rp = idx >> 4, ch = idx & 15;
          us8 v = *(const us8*)(lds + bC_ + rp*136 + ch*8);
          *(us8*)(H + (rowg + 64*c + rp)*(size_t)IDIM + ntcol + ch*8) = v;
        }
      }
      BAR;
    }
#pragma unroll
    for (int i2 = 0; i2 < 8; ++i2)
#pragma unroll
      for (int j2 = 0; j2 < 4; ++j2) acc[i2][j2] = (f32x4){0.f,0.f,0.f,0.f};
  }

#undef ITER
#undef QUAD
#undef LDB
#undef LDA
#undef STG
}

// =============== GEMM2: 256x128 8-phase deep pipeline (K=3072, 24 ITERs) =====
template<int KD>
__global__ __launch_bounds__(512, 2) void gemm2_8ph(
    const unsigned short* __restrict__ A,
    const unsigned short* __restrict__ Bw,
    unsigned short* __restrict__ O) {
  constexpr int NT = KD/64;        // 48
  constexpr int NITER = NT/2;      // 24
  __shared__ unsigned short lds[57344];

  const int bid = blockIdx.x;
  const int chunk = gridDim.x >> 3;
  const int tile = (bid & 7)*chunk + (bid >> 3);
  const int e = tile / 30;
  const int rem = tile % 30;
  const int nt = rem / 5, mt = rem % 5;

  const int tid = threadIdx.x;
  const int l = tid & 63, wid = tid >> 6;
  const int wr = wid >> 1, wc = wid & 1;
  const int lrow = l & 15, khi = l >> 4;

  const unsigned short* Ab = A  + (size_t)e*CAP*KD  + (size_t)mt*256*KD;
  const unsigned short* Bb = Bw + (size_t)e*CDIM*KD + (size_t)nt*128*KD;

  const int srow = tid >> 3;
  const int scol = (tid & 7) ^ (srow & 7);
  const size_t lane_off = (size_t)srow*KD + scol*8;
  const int lds_st = wid*512;

#define STG(dstu, srcp, half, kt) do { \
    const unsigned short* s_ = (srcp) + lane_off + (size_t)(half)*128*KD + (size_t)(kt)*64; \
    unsigned short* d_ = (unsigned short*)lds + (dstu) + (half)*8192 + lds_st; \
    __builtin_amdgcn_global_load_lds((const __attribute__((address_space(1))) void*)s_, \
        (__attribute__((address_space(3))) void*)d_, 16, 0, 0); \
    __builtin_amdgcn_global_load_lds((const __attribute__((address_space(1))) void*)(s_ + (size_t)64*KD), \
        (__attribute__((address_space(3))) void*)(d_ + 4096), 16, 0, 0); \
  } while(0)

  const int swz0 = ((khi    ) ^ (lrow & 7)) * 8;
  const int swz1 = ((4 + khi) ^ (lrow & 7)) * 8;
  const int aoff = wr*4096 + lrow*64;
  const int boff = wc*4096 + lrow*64;

#define LDA(ab, dst) do { _Pragma("unroll") for (int m_=0;m_<4;++m_) { \
    dst[m_][0] = *(const short8*)(lds + (ab) + aoff + m_*1024 + swz0); \
    dst[m_][1] = *(const short8*)(lds + (ab) + aoff + m_*1024 + swz1); } } while(0)
#define LDB(bb, dst, nb) do { _Pragma("unroll") for (int n_=0;n_<2;++n_) { \
    dst[n_][0] = *(const short8*)(lds + (bb) + boff + ((nb)+n_)*1024 + swz0); \
    dst[n_][1] = *(const short8*)(lds + (bb) + boff + ((nb)+n_)*1024 + swz1); } } while(0)
#define QUAD(af, bf, nb) do { _Pragma("unroll") for (int r_=0;r_<2;++r_) \
    _Pragma("unroll") for (int n_=0;n_<2;++n_) \
    _Pragma("unroll") for (int m_=0;m_<4;++m_) \
      acc[m_][(nb)+n_] = __builtin_amdgcn_mfma_f32_16x16x32_bf16(af[m_][r_], bf[n_][r_], acc[m_][(nb)+n_], 0,0,0); } while(0)

  f32x4 acc[4][4];
#pragma unroll
  for (int i = 0; i < 4; ++i)
#pragma unroll
    for (int j = 0; j < 4; ++j) acc[i][j] = (f32x4){0.f,0.f,0.f,0.f};

  short8 a[4][2], bl[2][2], bh[2][2];

  int bA_ = 32768, bB_ = 40960, bC_ = 49152;

  STG(0, Ab, 0, 0); STG(0, Ab, 1, 0); STG(bA_, Bb, 0, 0);
  STG(16384, Ab, 0, 1); STG(16384, Ab, 1, 1); STG(bB_, Bb, 0, 1);
  VMW(6);
  BAR;

#define ITER2(t2, t3, DOS, VM2, VM4) \
    LDA(0, a); LDB(bA_, bl, 0); if (DOS) STG(bC_, Bb, 0, (t2)); \
    BAR; P1; QUAD(a, bl, 0); P0; BAR; \
    LDB(bA_, bh, 2); if (DOS) { STG(0, Ab, 0, (t2)); STG(0, Ab, 1, (t2)); } VM2; \
    BAR; P1; QUAD(a, bh, 2); P0; BAR; \
    LDA(16384, a); LDB(bB_, bl, 0); if (DOS) STG(bA_, Bb, 0, (t3)); \
    BAR; P1; QUAD(a, bl, 0); P0; BAR; \
    LDB(bB_, bh, 2); if (DOS) { STG(16384, Ab, 0, (t3)); STG(16384, Ab, 1, (t3)); } VM4; \
    BAR; P1; QUAD(a, bh, 2); P0; BAR;

#pragma unroll 1
  for (int i = 0; i < NITER-1; ++i) {
    const int t2 = 2*i+2, t3 = 2*i+3;
    ITER2(t2, t3, true, VMW(6), VMW(6));
    int tmp = bC_; bC_ = bB_; bB_ = bA_; bA_ = tmp;
  }
  ITER2(0, 0, false, VMW(0), VMW(0));

#undef ITER2
#undef QUAD
#undef LDB
#undef LDA
#undef STG

  __syncthreads();
  {
    const int cb0 = wc*64 + lrow;
    const int rb0 = wr*64 + khi*4;
#pragma unroll
    for (int m = 0; m < 4; ++m)
#pragma unroll
      for (int n = 0; n < 4; ++n) {
        f32x4 v = acc[m][n];
#pragma unroll
        for (int r = 0; r < 4; ++r)
          lds[(rb0 + m*16 + r)*136 + cb0 + n*16] = f2b(v[r]);
      }
  }
  __syncthreads();
  const size_t rowg = (size_t)e*CAP + (size_t)mt*256;
  const size_t colg = (size_t)nt*128 + (size_t)(l & 15)*8;
#pragma unroll
  for (int i = 0; i < 8; ++i) {
    int row = wid*32 + i*4 + (l >> 4);
    us8 v = *(const us8*)(lds + row*136 + (l & 15)*8);
    *(us8*)(O + (rowg + row)*(size_t)CDIM + colg) = v;
  }
}

// ---------------- combine: grid-stride (bf16 expert outputs -> f32 y) --------
__global__ __launch_bounds__(256) void combine_kernel(const unsigned short* __restrict__ outbuf,
    const int* __restrict__ c1, const int* __restrict__ c2,
    const float* __restrict__ g1, const float* __restrict__ g2,
    float* __restrict__ y) {
  const int TOT = NTOK*(CDIM/4);
  for (int idx = blockIdx.x*256 + threadIdx.x; idx < TOT; idx += gridDim.x*256) {
    int t = idx / (CDIM/4), q = idx - t*(CDIM/4);
    float f1 = g1[t], f2 = g2[t];
    int a = c1[t], b = c2[t];
    us4 va = ((const us4*)outbuf)[(size_t)a*(CDIM/4) + q];
    us4 vb = ((const us4*)outbuf)[(size_t)b*(CDIM/4) + q];
    float4 r;
    r.x = f1*b2f(va.x) + f2*b2f(vb.x);
    r.y = f1*b2f(va.y) + f2*b2f(vb.y);
    r.z = f1*b2f(va.z) + f2*b2f(vb.z);
    r.w = f1*b2f(va.w) + f2*b2f(vb.w);
    ((float4*)y)[(size_t)t*(CDIM/4) + q] = r;
  }
}

extern "C" void kernel_launch(void* const* d_in, const int* in_sizes, int n_in,
                              void* d_out, int out_size, void* d_ws, size_t ws_size,
                              hipStream_t stream) {
  const float* x  = (const float*)d_in[0];
  const float* Wr = (const float*)d_in[1];
  const float* Wg = (const float*)d_in[2];
  const float* Wu = (const float*)d_in[3];
  const float* Wp = (const float*)d_in[4];
  float* y = (float*)d_out;

  char* p = (char*)d_ws;
  auto alloc = [&](size_t bytes) { char* r = p; p += (bytes + 255) & ~(size_t)255; return r; };
  unsigned short* WguT = (unsigned short*)alloc((size_t)NEXP*2*IDIM*CDIM*2);
  unsigned short* WpT  = (unsigned short*)alloc((size_t)NEXP*CDIM*IDIM*2);
  unsigned short* ein  = (unsigned short*)alloc((size_t)EROWS*CDIM*2);
  unsigned short* h    = (unsigned short*)alloc((size_t)EROWS*IDIM*2);
  unsigned short* outbuf = (unsigned short*)alloc((size_t)EROWS*CDIM*2);
  float* probs  = (float*)alloc((size_t)NTOK*NEXP*4);
  int* idx1 = (int*)alloc(NTOK*4);
  int* idx2 = (int*)alloc(NTOK*4);
  int* c1   = (int*)alloc(NTOK*4);
  int* c2   = (int*)alloc(NTOK*4);
  float* g1r = (float*)alloc(NTOK*4);
  float* g2r = (float*)alloc(NTOK*4);
  float* g1o = (float*)alloc(NTOK*4);
  float* g2o = (float*)alloc(NTOK*4);
  int* bufmap = (int*)alloc(EROWS*4);

  size_t required = (size_t)(p - (char*)d_ws);
  if (ws_size < required) return;

  const int NWGU = 2*NEXP*(CDIM/64)*(IDIM/64);   // 9216
  const int NWP  = NEXP*(IDIM/64)*(CDIM/64);     // 4608
  weights_cvt<<<NWGU + NWP, 256, 0, stream>>>(Wg, Wu, Wp, WguT, WpT);

  router_kernel<<<NTOK/4, 256, 0, stream>>>(x, Wr, probs, idx1, idx2, g1r, g2r);
  scan_kernel<<<1, 1024, 0, stream>>>(idx1, idx2, g1r, g2r, probs, bufmap,
                                      c1, c2, g1o, g2o, y + (size_t)NTOK*CDIM);
  dispatch_kernel<<<2048, 256, 0, stream>>>(x, bufmap, ein);

  gemm1_8ph<CDIM><<<240, 512, 0, stream>>>(ein, WguT, h);
  gemm2_8ph<IDIM><<<NEXP*5*(CDIM/128), 512, 0, stream>>>(h, WpT, outbuf);

  combine_kernel<<<2048, 256, 0, stream>>>(outbuf, c1, c2, g1o, g2o, y);
}

// Round 12
// 282.687 us; speedup vs baseline: 1.0888x; 1.0079x over previous
//
#include <hip/hip_runtime.h>
#include <cstdint>
#include <cstddef>

#define NTOK 8192
#define NEXP 8
#define CAP 1280
#define CDIM 768
#define IDIM 3072
#define EROWS (NEXP*CAP)   /* 10240 */

typedef __attribute__((ext_vector_type(8))) short short8;
typedef __attribute__((ext_vector_type(4))) float f32x4;
typedef __attribute__((ext_vector_type(4))) unsigned short us4;
typedef __attribute__((ext_vector_type(8))) unsigned short us8;

__device__ __forceinline__ unsigned short f2b(float f) {
  unsigned u = __builtin_bit_cast(unsigned, f);
  u += 0x7FFFu + ((u >> 16) & 1u);          // round-to-nearest-even
  return (unsigned short)(u >> 16);
}
__device__ __forceinline__ float b2f(unsigned short u) {
  return __builtin_bit_cast(float, ((unsigned)u) << 16);
}

// ======= fused prep: {Wg,Wu->Wgu^T} + {Wp->WpT} + router, one launch =========
// block-uniform branch on blockIdx; 24 KB shared LDS union.
// cvt: 64x64 f32 tile (stride 65), float4 reads, us8 stores (16B/lane).
__global__ __launch_bounds__(256) void prep_kernel(
    const float* __restrict__ Wg, const float* __restrict__ Wu,
    const float* __restrict__ Wp, const float* __restrict__ x,
    const float* __restrict__ Wr,
    unsigned short* __restrict__ Wgu, unsigned short* __restrict__ WpT,
    float* __restrict__ probs, int* __restrict__ idx1, int* __restrict__ idx2,
    float* __restrict__ g1r, float* __restrict__ g2r) {
  __shared__ float shm[NEXP*CDIM];               // 6144 f32 = 24 KB
  const int perEgu = (CDIM/64)*(IDIM/64);        // 576
  const int NWGU = 2*NEXP*perEgu;                // 9216
  const int NWP  = NEXP*perEgu;                  // 4608
  int bid = blockIdx.x;

  if (bid < NWGU + NWP) {
    // ---------------- transpose + f32->bf16 convert ----------------
    float* tile = shm;                           // [64][65] flat
    int c4 = (threadIdx.x & 15)*4, rr = threadIdx.x >> 4;
    const float* se;
    int sIsWgu = (bid < NWGU);
    int sel = 0, e, rt, st;
    if (sIsWgu) {
      sel = bid / (NEXP*perEgu);
      int rem = bid % (NEXP*perEgu);
      e = rem / perEgu; int r2 = rem % perEgu;
      rt = r2 / (IDIM/64); st = r2 % (IDIM/64);
      se = (sel ? Wu : Wg) + (size_t)e*CDIM*IDIM + ((size_t)rt*64)*IDIM + st*64;
#pragma unroll
      for (int p = 0; p < 4; ++p) {
        float4 v = *(const float4*)(se + (size_t)(rr + 16*p)*IDIM + c4);
        tile[(rr + 16*p)*65 + c4+0] = v.x; tile[(rr + 16*p)*65 + c4+1] = v.y;
        tile[(rr + 16*p)*65 + c4+2] = v.z; tile[(rr + 16*p)*65 + c4+3] = v.w;
      }
    } else {
      int b2 = bid - NWGU;
      const int tilesS = CDIM/64;                // 12
      e = b2 / perEgu; int rem2 = b2 % perEgu;
      rt = rem2 / tilesS; st = rem2 % tilesS;
      se = Wp + (size_t)e*IDIM*CDIM + ((size_t)rt*64)*CDIM + st*64;
#pragma unroll
      for (int p = 0; p < 4; ++p) {
        float4 v = *(const float4*)(se + (size_t)(rr + 16*p)*CDIM + c4);
        tile[(rr + 16*p)*65 + c4+0] = v.x; tile[(rr + 16*p)*65 + c4+1] = v.y;
        tile[(rr + 16*p)*65 + c4+2] = v.z; tile[(rr + 16*p)*65 + c4+3] = v.w;
      }
    }
    __syncthreads();
    int ch = threadIdx.x & 7, sr = threadIdx.x >> 3;   // chunk 0..7, row 0..31
    if (sIsWgu) {
      unsigned short* dstE = Wgu + (size_t)e*(2*IDIM)*CDIM;
#pragma unroll
      for (int q = 0; q < 2; ++q) {
        int s = sr + 32*q;
        int np = 128*st + 32*(s>>4) + (s&15) + sel*16;
        us8 o;
#pragma unroll
        for (int k = 0; k < 8; ++k) o[k] = f2b(tile[(ch*8+k)*65 + s]);
        *(us8*)(dstE + (size_t)np*CDIM + rt*64 + ch*8) = o;
      }
    } else {
      unsigned short* de = WpT + (size_t)e*IDIM*CDIM + ((size_t)st*64)*IDIM + rt*64;
#pragma unroll
      for (int q = 0; q < 2; ++q) {
        int s = sr + 32*q;
        us8 o;
#pragma unroll
        for (int k = 0; k < 8; ++k) o[k] = f2b(tile[(ch*8+k)*65 + s]);
        *(us8*)(de + (size_t)s*IDIM + ch*8) = o;
      }
    }
  } else {
    // ---------------- router: logits, softmax, top-2, raw gates -------------
    int rid = bid - (NWGU + NWP);
    for (int i = threadIdx.x; i < NEXP*CDIM; i += 256) {
      int c = i >> 3, e = i & 7;
      shm[e*CDIM + c] = Wr[i];
    }
    __syncthreads();
    int w = threadIdx.x >> 6, l = threadIdx.x & 63;
    int t = rid*4 + w;
    float acc[NEXP];
#pragma unroll
    for (int e = 0; e < NEXP; ++e) acc[e] = 0.f;
    for (int k = 0; k < CDIM/64; ++k) {
      float xv = x[(size_t)t*CDIM + k*64 + l];
#pragma unroll
      for (int e = 0; e < NEXP; ++e) acc[e] += xv * shm[e*CDIM + k*64 + l];
    }
#pragma unroll
    for (int off = 32; off > 0; off >>= 1) {
#pragma unroll
      for (int e = 0; e < NEXP; ++e) acc[e] += __shfl_xor(acc[e], off);
    }
    if (l == 0) {
      float m = acc[0];
#pragma unroll
      for (int e = 1; e < NEXP; ++e) m = fmaxf(m, acc[e]);
      float p[NEXP]; float s = 0.f;
#pragma unroll
      for (int e = 0; e < NEXP; ++e) { p[e] = expf(acc[e] - m); s += p[e]; }
      float inv = 1.f / s;
#pragma unroll
      for (int e = 0; e < NEXP; ++e) { p[e] *= inv; probs[(size_t)t*NEXP + e] = p[e]; }
      int i1 = 0; float b1 = p[0];
#pragma unroll
      for (int e = 1; e < NEXP; ++e) if (p[e] > b1) { b1 = p[e]; i1 = e; }
      int i2 = -1; float b2 = -1e30f;
#pragma unroll
      for (int e = 0; e < NEXP; ++e) if (e != i1 && p[e] > b2) { b2 = p[e]; i2 = e; }
      float gs = fmaxf(b1 + b2, 1e-9f);
      g1r[t] = b1 / gs; g2r[t] = b2 / gs;
      idx1[t] = i1; idx2[t] = i2;
    }
  }
}

// ---------------- scan (also initializes bufmap to -1) ----------------
__global__ __launch_bounds__(1024) void scan_kernel(
    const int* __restrict__ idx1, const int* __restrict__ idx2,
    const float* __restrict__ g1r, const float* __restrict__ g2r,
    const float* __restrict__ probs,
    int* __restrict__ bufmap,
    int* __restrict__ c1o, int* __restrict__ c2o,
    float* __restrict__ g1o, float* __restrict__ g2o,
    float* __restrict__ aux_out) {
  __shared__ unsigned int scanbuf[1024][9];
  __shared__ unsigned int totals[NEXP];
  int tid = threadIdx.x;
  for (int i = tid; i < EROWS; i += 1024) bufmap[i] = -1;
  int e1[8], e2[8];
  unsigned int cnt[NEXP];
#pragma unroll
  for (int k = 0; k < NEXP; ++k) cnt[k] = 0;
  for (int j = 0; j < 8; ++j) {
    int t = tid*8 + j;
    e1[j] = idx1[t]; e2[j] = idx2[t];
    cnt[e1[j]] += 1u;
    cnt[e2[j]] += (1u << 16);
  }
#pragma unroll
  for (int k = 0; k < NEXP; ++k) scanbuf[tid][k] = cnt[k];
  unsigned int run[NEXP];
#pragma unroll
  for (int k = 0; k < NEXP; ++k) run[k] = cnt[k];
  __syncthreads();
  for (int off = 1; off < 1024; off <<= 1) {
    unsigned int add[NEXP];
#pragma unroll
    for (int k = 0; k < NEXP; ++k) add[k] = 0;
    if (tid >= off) {
#pragma unroll
      for (int k = 0; k < NEXP; ++k) add[k] = scanbuf[tid - off][k];
    }
    __syncthreads();
#pragma unroll
    for (int k = 0; k < NEXP; ++k) { run[k] += add[k]; scanbuf[tid][k] = run[k]; }
    __syncthreads();
  }
  if (tid == 1023) {
#pragma unroll
    for (int k = 0; k < NEXP; ++k) totals[k] = run[k];
  }
  __syncthreads();
  unsigned int excl[NEXP];
#pragma unroll
  for (int k = 0; k < NEXP; ++k) excl[k] = run[k] - cnt[k];
  int cnt1c[NEXP];
#pragma unroll
  for (int k = 0; k < NEXP; ++k) cnt1c[k] = min((int)(totals[k] & 0xFFFFu), CAP);

  for (int j = 0; j < 8; ++j) {
    int t = tid*8 + j;
    int a = e1[j];
    int pos1 = (int)(excl[a] & 0xFFFFu); excl[a] += 1u;
    int slot1 = a*CAP + pos1;
    bool m1 = pos1 < CAP;
    if (m1) bufmap[slot1] = t;
    int b = e2[j];
    int pos2 = (int)(excl[b] >> 16) + cnt1c[b]; excl[b] += (1u << 16);
    int slot2 = b*CAP + pos2;
    bool m2 = pos2 < CAP;
    if (m2) bufmap[slot2] = t;
    float G1 = m1 ? g1r[t] : 0.f;
    float G2 = m2 ? g2r[t] : 0.f;
    float den = fmaxf(G1 + G2, 1e-9f);
    g1o[t] = G1 / den; g2o[t] = G2 / den;
    c1o[t] = min(slot1, EROWS - 1);
    c2o[t] = min(slot2, EROWS - 1);
  }

  float imp[NEXP];
#pragma unroll
  for (int k = 0; k < NEXP; ++k) imp[k] = 0.f;
  for (int j = 0; j < 8; ++j) {
    int t = tid*8 + j;
    const float4* pr = (const float4*)(probs + (size_t)t*NEXP);
    float4 a0 = pr[0], a1 = pr[1];
    imp[0] += a0.x; imp[1] += a0.y; imp[2] += a0.z; imp[3] += a0.w;
    imp[4] += a1.x; imp[5] += a1.y; imp[6] += a1.z; imp[7] += a1.w;
  }
  __syncthreads();
  float* fbuf = (float*)&scanbuf[0][0];
#pragma unroll
  for (int k = 0; k < NEXP; ++k) fbuf[tid*9 + k] = imp[k];
  __syncthreads();
  for (int s = 512; s >= 1; s >>= 1) {
    if (tid < s) {
#pragma unroll
      for (int k = 0; k < NEXP; ++k) fbuf[tid*9 + k] += fbuf[(tid + s)*9 + k];
    }
    __syncthreads();
  }
  if (tid == 0) {
    float aux = 0.f;
#pragma unroll
    for (int k = 0; k < NEXP; ++k) {
      float importance = fbuf[k] / (float)NTOK;
      float loadk = (float)((totals[k] & 0xFFFFu) + (totals[k] >> 16)) / ((float)NTOK * 2.0f);
      aux += importance * loadk;
    }
    aux_out[0] = aux * (float)NEXP * 0.01f;
  }
}

// ---------------- dispatch: grid-stride gather x -> ein (bf16) ----------------
__global__ __launch_bounds__(256) void dispatch_kernel(const float* __restrict__ x,
    const int* __restrict__ bufmap, unsigned short* __restrict__ ein) {
  const int TOT = EROWS*(CDIM/4);
  for (int idx = blockIdx.x*256 + threadIdx.x; idx < TOT; idx += gridDim.x*256) {
    int r = idx / (CDIM/4), q = idx - r*(CDIM/4);
    int t = bufmap[r];
    float4 v = make_float4(0.f, 0.f, 0.f, 0.f);
    if (t >= 0) v = ((const float4*)x)[(size_t)t*(CDIM/4) + q];
    us4 o;
    o.x = f2b(v.x); o.y = f2b(v.y); o.z = f2b(v.z); o.w = f2b(v.w);
    ((us4*)ein)[(size_t)r*(CDIM/4) + q] = o;
  }
}

#define BAR  asm volatile("s_barrier" ::: "memory")
#define VMW(N) asm volatile("s_waitcnt vmcnt(" #N ")" ::: "memory")
#define LGW  asm volatile("s_waitcnt lgkmcnt(0)" ::: "memory")
#define P1 __builtin_amdgcn_s_setprio(1)
#define P0 __builtin_amdgcn_s_setprio(0)

// =============== GEMM1: persistent 256x256 8-phase (r9, verified 117us) ======
template<int KD>
__global__ __launch_bounds__(512, 2) void gemm1_8ph(
    const unsigned short* __restrict__ A,
    const unsigned short* __restrict__ Bw,
    unsigned short* __restrict__ H) {
  __shared__ unsigned short lds[81920];
  constexpr size_t JSTR = (size_t)6*256*KD;

  const int bid = blockIdx.x;
  const int chunk = gridDim.x >> 3;
  const int tile = (bid & 7)*chunk + (bid >> 3);
  const int e = tile / 30;
  const int r30 = tile % 30;
  const int ntb = r30 / 5, mt = r30 % 5;

  const int tid = threadIdx.x;
  const int l = tid & 63, wid = tid >> 6;
  const int wr = wid >> 2, wc = wid & 3;
  const int lrow = l & 15, khi = l >> 4;

  const unsigned short* Ab = A  + (size_t)e*CAP*KD      + (size_t)mt*256*KD;
  const unsigned short* Bb = Bw + (size_t)e*(2*IDIM)*KD + (size_t)ntb*256*KD;

  const int srow = tid >> 3;
  const int scol = (tid & 7) ^ (srow & 7);
  const size_t lane_off = (size_t)srow*KD + scol*8;
  const int lds_st = wid*512;

#define STG(dstu, srcp, half, kt) do { \
    const unsigned short* s_ = (srcp) + lane_off + (size_t)(half)*128*KD + (size_t)(kt)*64; \
    unsigned short* d_ = (unsigned short*)lds + (dstu) + (half)*8192 + lds_st; \
    __builtin_amdgcn_global_load_lds((const __attribute__((address_space(1))) void*)s_, \
        (__attribute__((address_space(3))) void*)d_, 16, 0, 0); \
    __builtin_amdgcn_global_load_lds((const __attribute__((address_space(1))) void*)(s_ + (size_t)64*KD), \
        (__attribute__((address_space(3))) void*)(d_ + 4096), 16, 0, 0); \
  } while(0)

  const int swz0 = ((khi    ) ^ (lrow & 7)) * 8;
  const int swz1 = ((4 + khi) ^ (lrow & 7)) * 8;
  const int aoff = wr*8192 + lrow*64;
  const int boff = (wc>>1)*8192 + ((wc&1)*64 + lrow)*64;

#define LDA(ab, dst, mb) do { _Pragma("unroll") for (int m_=0;m_<4;++m_) { \
    dst[m_][0] = *(const short8*)(lds + (ab) + aoff + ((mb)+m_)*1024 + swz0); \
    dst[m_][1] = *(const short8*)(lds + (ab) + aoff + ((mb)+m_)*1024 + swz1); } } while(0)
#define LDB(bb, dst, nb) do { _Pragma("unroll") for (int n_=0;n_<2;++n_) { \
    dst[n_][0] = *(const short8*)(lds + (bb) + boff + ((nb)+n_)*1024 + swz0); \
    dst[n_][1] = *(const short8*)(lds + (bb) + boff + ((nb)+n_)*1024 + swz1); } } while(0)
#define QUAD(af, bf, mb, nb) do { _Pragma("unroll") for (int r_=0;r_<2;++r_) \
    _Pragma("unroll") for (int n_=0;n_<2;++n_) \
    _Pragma("unroll") for (int m_=0;m_<4;++m_) \
      acc[(mb)+m_][(nb)+n_] = __builtin_amdgcn_mfma_f32_16x16x32_bf16(af[m_][r_], bf[n_][r_], acc[(mb)+m_][(nb)+n_], 0,0,0); } while(0)

  f32x4 acc[8][4];
#pragma unroll
  for (int i = 0; i < 8; ++i)
#pragma unroll
    for (int j = 0; j < 4; ++j) acc[i][j] = (f32x4){0.f,0.f,0.f,0.f};

  short8 a[4][2], bl[2][2], bh[2][2];

  int bA_ = 32768, bB_ = 49152, bC_ = 65536;

  STG(0, Ab, 0, 0);      STG(bA_, Bb, 0, 0);
  STG(0, Ab, 1, 0);      STG(bA_, Bb, 1, 0);
  STG(16384, Ab, 0, 1);  STG(bB_, Bb, 0, 1);
  STG(16384, Ab, 1, 1);  STG(bB_, Bb, 1, 1);
  VMW(8);
  BAR;

#define ITER(k2p, B2) \
    LDA(0, a, 0); LDB(bA_, bl, 0); STG(bC_, (B2), 0, (k2p)); \
    BAR; P1; QUAD(a, bl, 0, 0); P0; BAR; \
    LDB(bA_, bh, 2); STG(bC_, (B2), 1, (k2p)); \
    BAR; P1; QUAD(a, bh, 0, 2); P0; BAR; \
    LDA(0, a, 4); \
    BAR; P1; QUAD(a, bh, 4, 2); P0; BAR; \
    STG(0, Ab, 0, (k2p)); VMW(6); \
    BAR; P1; QUAD(a, bl, 4, 0); P0; BAR; \
    LDA(16384, a, 0); LDB(bB_, bl, 0); STG(0, Ab, 1, (k2p)); STG(bA_, (B2), 0, (k2p)+1); \
    BAR; P1; QUAD(a, bl, 0, 0); P0; BAR; \
    LDB(bB_, bh, 2); STG(bA_, (B2), 1, (k2p)+1); \
    BAR; P1; QUAD(a, bh, 0, 2); P0; BAR; \
    LDA(16384, a, 4); \
    BAR; P1; QUAD(a, bh, 4, 2); P0; BAR; \
    STG(16384, Ab, 0, (k2p)+1); STG(16384, Ab, 1, (k2p)+1); VMW(8); \
    BAR; P1; QUAD(a, bl, 4, 0); P0; BAR;

  const size_t rowg = (size_t)e*CAP + (size_t)mt*256;
  int itr = 0;

#pragma unroll 1
  for (int j = 0; j < 4; ++j) {
#pragma unroll 1
    for (int ii = 0; ii < 6; ++ii) {
      int t2 = 2*itr + 2;
      if (t2 >= 48) t2 = 0;                      // tail wrap (garbage stage)
      int j2 = t2 / 12, k2 = t2 - j2*12;
      const unsigned short* B2 = Bb + (size_t)j2*JSTR;
      ITER(k2, B2);
      int tmp = bC_; bC_ = bB_; bB_ = bA_; bA_ = tmp;
      ++itr;
    }
    {
      const size_t ntcol = (size_t)(ntb + 6*j)*128;
#pragma unroll
      for (int c = 0; c < 4; ++c) {
        BAR;
        if (wr == (c >> 1)) {
#pragma unroll
          for (int m_ = 0; m_ < 4; ++m_) {
#pragma unroll
            for (int p = 0; p < 2; ++p) {
              f32x4 g = acc[(c & 1)*4 + m_][2*p], u = acc[(c & 1)*4 + m_][2*p+1];
#pragma unroll
              for (int r = 0; r < 4; ++r) {
                float gv = g[r];
                float hv = gv / (1.f + __expf(-gv)) * u[r];
                lds[bC_ + (m_*16 + khi*4 + r)*136 + wc*32 + lrow + p*16] = f2b(hv);
              }
            }
          }
        }
        LGW;
        BAR;
#pragma unroll
        for (int q = 0; q < 2; ++q) {
          int idx = tid + 512*q;
          int rp = idx >> 4, ch = idx & 15;
          us8 v = *(const us8*)(lds + bC_ + rp*136 + ch*8);
          *(us8*)(H + (rowg + 64*c + rp)*(size_t)IDIM + ntcol + ch*8) = v;
        }
      }
      BAR;
    }
#pragma unroll
    for (int i2 = 0; i2 < 8; ++i2)
#pragma unroll
      for (int j2 = 0; j2 < 4; ++j2) acc[i2][j2] = (f32x4){0.f,0.f,0.f,0.f};
  }

#undef ITER
#undef QUAD
#undef LDB
#undef LDA
#undef STG
}

// =============== GEMM2: 256x128 8-phase deep pipeline (K=3072, 24 ITERs) =====
template<int KD>
__global__ __launch_bounds__(512, 2) void gemm2_8ph(
    const unsigned short* __restrict__ A,
    const unsigned short* __restrict__ Bw,
    unsigned short* __restrict__ O) {
  constexpr int NT = KD/64;        // 48
  constexpr int NITER = NT/2;      // 24
  __shared__ unsigned short lds[57344];

  const int bid = blockIdx.x;
  const int chunk = gridDim.x >> 3;
  const int tile = (bid & 7)*chunk + (bid >> 3);
  const int e = tile / 30;
  const int rem = tile % 30;
  const int nt = rem / 5, mt = rem % 5;

  const int tid = threadIdx.x;
  const int l = tid & 63, wid = tid >> 6;
  const int wr = wid >> 1, wc = wid & 1;
  const int lrow = l & 15, khi = l >> 4;

  const unsigned short* Ab = A  + (size_t)e*CAP*KD  + (size_t)mt*256*KD;
  const unsigned short* Bb = Bw + (size_t)e*CDIM*KD + (size_t)nt*128*KD;

  const int srow = tid >> 3;
  const int scol = (tid & 7) ^ (srow & 7);
  const size_t lane_off = (size_t)srow*KD + scol*8;
  const int lds_st = wid*512;

#define STG(dstu, srcp, half, kt) do { \
    const unsigned short* s_ = (srcp) + lane_off + (size_t)(half)*128*KD + (size_t)(kt)*64; \
    unsigned short* d_ = (unsigned short*)lds + (dstu) + (half)*8192 + lds_st; \
    __builtin_amdgcn_global_load_lds((const __attribute__((address_space(1))) void*)s_, \
        (__attribute__((address_space(3))) void*)d_, 16, 0, 0); \
    __builtin_amdgcn_global_load_lds((const __attribute__((address_space(1))) void*)(s_ + (size_t)64*KD), \
        (__attribute__((address_space(3))) void*)(d_ + 4096), 16, 0, 0); \
  } while(0)

  const int swz0 = ((khi    ) ^ (lrow & 7)) * 8;
  const int swz1 = ((4 + khi) ^ (lrow & 7)) * 8;
  const int aoff = wr*4096 + lrow*64;
  const int boff = wc*4096 + lrow*64;

#define LDA(ab, dst) do { _Pragma("unroll") for (int m_=0;m_<4;++m_) { \
    dst[m_][0] = *(const short8*)(lds + (ab) + aoff + m_*1024 + swz0); \
    dst[m_][1] = *(const short8*)(lds + (ab) + aoff + m_*1024 + swz1); } } while(0)
#define LDB(bb, dst, nb) do { _Pragma("unroll") for (int n_=0;n_<2;++n_) { \
    dst[n_][0] = *(const short8*)(lds + (bb) + boff + ((nb)+n_)*1024 + swz0); \
    dst[n_][1] = *(const short8*)(lds + (bb) + boff + ((nb)+n_)*1024 + swz1); } } while(0)
#define QUAD(af, bf, nb) do { _Pragma("unroll") for (int r_=0;r_<2;++r_) \
    _Pragma("unroll") for (int n_=0;n_<2;++n_) \
    _Pragma("unroll") for (int m_=0;m_<4;++m_) \
      acc[m_][(nb)+n_] = __builtin_amdgcn_mfma_f32_16x16x32_bf16(af[m_][r_], bf[n_][r_], acc[m_][(nb)+n_], 0,0,0); } while(0)

  f32x4 acc[4][4];
#pragma unroll
  for (int i = 0; i < 4; ++i)
#pragma unroll
    for (int j = 0; j < 4; ++j) acc[i][j] = (f32x4){0.f,0.f,0.f,0.f};

  short8 a[4][2], bl[2][2], bh[2][2];

  int bA_ = 32768, bB_ = 40960, bC_ = 49152;

  STG(0, Ab, 0, 0); STG(0, Ab, 1, 0); STG(bA_, Bb, 0, 0);
  STG(16384, Ab, 0, 1); STG(16384, Ab, 1, 1); STG(bB_, Bb, 0, 1);
  VMW(6);
  BAR;

#define ITER2(t2, t3, DOS, VM2, VM4) \
    LDA(0, a); LDB(bA_, bl, 0); if (DOS) STG(bC_, Bb, 0, (t2)); \
    BAR; P1; QUAD(a, bl, 0); P0; BAR; \
    LDB(bA_, bh, 2); if (DOS) { STG(0, Ab, 0, (t2)); STG(0, Ab, 1, (t2)); } VM2; \
    BAR; P1; QUAD(a, bh, 2); P0; BAR; \
    LDA(16384, a); LDB(bB_, bl, 0); if (DOS) STG(bA_, Bb, 0, (t3)); \
    BAR; P1; QUAD(a, bl, 0); P0; BAR; \
    LDB(bB_, bh, 2); if (DOS) { STG(16384, Ab, 0, (t3)); STG(16384, Ab, 1, (t3)); } VM4; \
    BAR; P1; QUAD(a, bh, 2); P0; BAR;

#pragma unroll 1
  for (int i = 0; i < NITER-1; ++i) {
    const int t2 = 2*i+2, t3 = 2*i+3;
    ITER2(t2, t3, true, VMW(6), VMW(6));
    int tmp = bC_; bC_ = bB_; bB_ = bA_; bA_ = tmp;
  }
  ITER2(0, 0, false, VMW(0), VMW(0));

#undef ITER2
#undef QUAD
#undef LDB
#undef LDA
#undef STG

  __syncthreads();
  {
    const int cb0 = wc*64 + lrow;
    const int rb0 = wr*64 + khi*4;
#pragma unroll
    for (int m = 0; m < 4; ++m)
#pragma unroll
      for (int n = 0; n < 4; ++n) {
        f32x4 v = acc[m][n];
#pragma unroll
        for (int r = 0; r < 4; ++r)
          lds[(rb0 + m*16 + r)*136 + cb0 + n*16] = f2b(v[r]);
      }
  }
  __syncthreads();
  const size_t rowg = (size_t)e*CAP + (size_t)mt*256;
  const size_t colg = (size_t)nt*128 + (size_t)(l & 15)*8;
#pragma unroll
  for (int i = 0; i < 8; ++i) {
    int row = wid*32 + i*4 + (l >> 4);
    us8 v = *(const us8*)(lds + row*136 + (l & 15)*8);
    *(us8*)(O + (rowg + row)*(size_t)CDIM + colg) = v;
  }
}

// ---------------- combine: grid-stride (bf16 expert outputs -> f32 y) --------
__global__ __launch_bounds__(256) void combine_kernel(const unsigned short* __restrict__ outbuf,
    const int* __restrict__ c1, const int* __restrict__ c2,
    const float* __restrict__ g1, const float* __restrict__ g2,
    float* __restrict__ y) {
  const int TOT = NTOK*(CDIM/4);
  for (int idx = blockIdx.x*256 + threadIdx.x; idx < TOT; idx += gridDim.x*256) {
    int t = idx / (CDIM/4), q = idx - t*(CDIM/4);
    float f1 = g1[t], f2 = g2[t];
    int a = c1[t], b = c2[t];
    us4 va = ((const us4*)outbuf)[(size_t)a*(CDIM/4) + q];
    us4 vb = ((const us4*)outbuf)[(size_t)b*(CDIM/4) + q];
    float4 r;
    r.x = f1*b2f(va.x) + f2*b2f(vb.x);
    r.y = f1*b2f(va.y) + f2*b2f(vb.y);
    r.z = f1*b2f(va.z) + f2*b2f(vb.z);
    r.w = f1*b2f(va.w) + f2*b2f(vb.w);
    ((float4*)y)[(size_t)t*(CDIM/4) + q] = r;
  }
}

extern "C" void kernel_launch(void* const* d_in, const int* in_sizes, int n_in,
                              void* d_out, int out_size, void* d_ws, size_t ws_size,
                              hipStream_t stream) {
  const float* x  = (const float*)d_in[0];
  const float* Wr = (const float*)d_in[1];
  const float* Wg = (const float*)d_in[2];
  const float* Wu = (const float*)d_in[3];
  const float* Wp = (const float*)d_in[4];
  float* y = (float*)d_out;

  char* p = (char*)d_ws;
  auto alloc = [&](size_t bytes) { char* r = p; p += (bytes + 255) & ~(size_t)255; return r; };
  unsigned short* WguT = (unsigned short*)alloc((size_t)NEXP*2*IDIM*CDIM*2);
  unsigned short* WpT  = (unsigned short*)alloc((size_t)NEXP*CDIM*IDIM*2);
  unsigned short* ein  = (unsigned short*)alloc((size_t)EROWS*CDIM*2);
  unsigned short* h    = (unsigned short*)alloc((size_t)EROWS*IDIM*2);
  unsigned short* outbuf = (unsigned short*)alloc((size_t)EROWS*CDIM*2);
  float* probs  = (float*)alloc((size_t)NTOK*NEXP*4);
  int* idx1 = (int*)alloc(NTOK*4);
  int* idx2 = (int*)alloc(NTOK*4);
  int* c1   = (int*)alloc(NTOK*4);
  int* c2   = (int*)alloc(NTOK*4);
  float* g1r = (float*)alloc(NTOK*4);
  float* g2r = (float*)alloc(NTOK*4);
  float* g1o = (float*)alloc(NTOK*4);
  float* g2o = (float*)alloc(NTOK*4);
  int* bufmap = (int*)alloc(EROWS*4);

  size_t required = (size_t)(p - (char*)d_ws);
  if (ws_size < required) return;

  const int NWGU = 2*NEXP*(CDIM/64)*(IDIM/64);   // 9216
  const int NWP  = NEXP*(IDIM/64)*(CDIM/64);     // 4608
  prep_kernel<<<NWGU + NWP + NTOK/4, 256, 0, stream>>>(
      Wg, Wu, Wp, x, Wr, WguT, WpT, probs, idx1, idx2, g1r, g2r);

  scan_kernel<<<1, 1024, 0, stream>>>(idx1, idx2, g1r, g2r, probs, bufmap,
                                      c1, c2, g1o, g2o, y + (size_t)NTOK*CDIM);
  dispatch_kernel<<<2048, 256, 0, stream>>>(x, bufmap, ein);

  gemm1_8ph<CDIM><<<240, 512, 0, stream>>>(ein, WguT, h);
  gemm2_8ph<IDIM><<<NEXP*5*(CDIM/128), 512, 0, stream>>>(h, WpT, outbuf);

  combine_kernel<<<2048, 256, 0, stream>>>(outbuf, c1, c2, g1o, g2o, y);
}

// Round 13
// 272.363 us; speedup vs baseline: 1.1301x; 1.0379x over previous
//
#include <hip/hip_runtime.h>
#include <cstdint>
#include <cstddef>

#define NTOK 8192
#define NEXP 8
#define CAP 1280
#define CDIM 768
#define IDIM 3072
#define EROWS (NEXP*CAP)   /* 10240 */

typedef __attribute__((ext_vector_type(8))) short short8;
typedef __attribute__((ext_vector_type(4))) float f32x4;
typedef __attribute__((ext_vector_type(4))) unsigned short us4;
typedef __attribute__((ext_vector_type(8))) unsigned short us8;

__device__ __forceinline__ unsigned short f2b(float f) {
  unsigned u = __builtin_bit_cast(unsigned, f);
  u += 0x7FFFu + ((u >> 16) & 1u);          // round-to-nearest-even
  return (unsigned short)(u >> 16);
}
__device__ __forceinline__ float b2f(unsigned short u) {
  return __builtin_bit_cast(float, ((unsigned)u) << 16);
}

// ======= fused prep: {Wg,Wu->Wgu^T} + {Wp->WpT} + router (+imp partials) =====
__global__ __launch_bounds__(256) void prep_kernel(
    const float* __restrict__ Wg, const float* __restrict__ Wu,
    const float* __restrict__ Wp, const float* __restrict__ x,
    const float* __restrict__ Wr,
    unsigned short* __restrict__ Wgu, unsigned short* __restrict__ WpT,
    float* __restrict__ impart, int* __restrict__ idx1, int* __restrict__ idx2,
    float* __restrict__ g1r, float* __restrict__ g2r) {
  __shared__ float shm[NEXP*CDIM + 32];          // 24 KB + partial slots
  const int perEgu = (CDIM/64)*(IDIM/64);        // 576
  const int NWGU = 2*NEXP*perEgu;                // 9216
  const int NWP  = NEXP*perEgu;                  // 4608
  int bid = blockIdx.x;

  if (bid < NWGU + NWP) {
    // ---------------- transpose + f32->bf16 convert ----------------
    float* tile = shm;                           // [64][65] flat
    int c4 = (threadIdx.x & 15)*4, rr = threadIdx.x >> 4;
    const float* se;
    int sIsWgu = (bid < NWGU);
    int sel = 0, e, rt, st;
    if (sIsWgu) {
      sel = bid / (NEXP*perEgu);
      int rem = bid % (NEXP*perEgu);
      e = rem / perEgu; int r2 = rem % perEgu;
      rt = r2 / (IDIM/64); st = r2 % (IDIM/64);
      se = (sel ? Wu : Wg) + (size_t)e*CDIM*IDIM + ((size_t)rt*64)*IDIM + st*64;
#pragma unroll
      for (int p = 0; p < 4; ++p) {
        float4 v = *(const float4*)(se + (size_t)(rr + 16*p)*IDIM + c4);
        tile[(rr + 16*p)*65 + c4+0] = v.x; tile[(rr + 16*p)*65 + c4+1] = v.y;
        tile[(rr + 16*p)*65 + c4+2] = v.z; tile[(rr + 16*p)*65 + c4+3] = v.w;
      }
    } else {
      int b2 = bid - NWGU;
      const int tilesS = CDIM/64;                // 12
      e = b2 / perEgu; int rem2 = b2 % perEgu;
      rt = rem2 / tilesS; st = rem2 % tilesS;
      se = Wp + (size_t)e*IDIM*CDIM + ((size_t)rt*64)*CDIM + st*64;
#pragma unroll
      for (int p = 0; p < 4; ++p) {
        float4 v = *(const float4*)(se + (size_t)(rr + 16*p)*CDIM + c4);
        tile[(rr + 16*p)*65 + c4+0] = v.x; tile[(rr + 16*p)*65 + c4+1] = v.y;
        tile[(rr + 16*p)*65 + c4+2] = v.z; tile[(rr + 16*p)*65 + c4+3] = v.w;
      }
    }
    __syncthreads();
    int ch = threadIdx.x & 7, sr = threadIdx.x >> 3;   // chunk 0..7, row 0..31
    if (sIsWgu) {
      unsigned short* dstE = Wgu + (size_t)e*(2*IDIM)*CDIM;
#pragma unroll
      for (int q = 0; q < 2; ++q) {
        int s = sr + 32*q;
        int np = 128*st + 32*(s>>4) + (s&15) + sel*16;
        us8 o;
#pragma unroll
        for (int k = 0; k < 8; ++k) o[k] = f2b(tile[(ch*8+k)*65 + s]);
        *(us8*)(dstE + (size_t)np*CDIM + rt*64 + ch*8) = o;
      }
    } else {
      unsigned short* de = WpT + (size_t)e*IDIM*CDIM + ((size_t)st*64)*IDIM + rt*64;
#pragma unroll
      for (int q = 0; q < 2; ++q) {
        int s = sr + 32*q;
        us8 o;
#pragma unroll
        for (int k = 0; k < 8; ++k) o[k] = f2b(tile[(ch*8+k)*65 + s]);
        *(us8*)(de + (size_t)s*IDIM + ch*8) = o;
      }
    }
  } else {
    // ---------------- router + per-block importance partials ----------------
    int rid = bid - (NWGU + NWP);
    for (int i = threadIdx.x; i < NEXP*CDIM; i += 256) {
      int c = i >> 3, e = i & 7;
      shm[e*CDIM + c] = Wr[i];
    }
    __syncthreads();
    int w = threadIdx.x >> 6, l = threadIdx.x & 63;
    int t = rid*4 + w;
    float acc[NEXP];
#pragma unroll
    for (int e = 0; e < NEXP; ++e) acc[e] = 0.f;
    for (int k = 0; k < CDIM/64; ++k) {
      float xv = x[(size_t)t*CDIM + k*64 + l];
#pragma unroll
      for (int e = 0; e < NEXP; ++e) acc[e] += xv * shm[e*CDIM + k*64 + l];
    }
#pragma unroll
    for (int off = 32; off > 0; off >>= 1) {
#pragma unroll
      for (int e = 0; e < NEXP; ++e) acc[e] += __shfl_xor(acc[e], off);
    }
    if (l == 0) {
      float m = acc[0];
#pragma unroll
      for (int e = 1; e < NEXP; ++e) m = fmaxf(m, acc[e]);
      float p[NEXP]; float s = 0.f;
#pragma unroll
      for (int e = 0; e < NEXP; ++e) { p[e] = expf(acc[e] - m); s += p[e]; }
      float inv = 1.f / s;
#pragma unroll
      for (int e = 0; e < NEXP; ++e) { p[e] *= inv; shm[NEXP*CDIM + w*8 + e] = p[e]; }
      int i1 = 0; float b1 = p[0];
#pragma unroll
      for (int e = 1; e < NEXP; ++e) if (p[e] > b1) { b1 = p[e]; i1 = e; }
      int i2 = -1; float b2 = -1e30f;
#pragma unroll
      for (int e = 0; e < NEXP; ++e) if (e != i1 && p[e] > b2) { b2 = p[e]; i2 = e; }
      float gs = fmaxf(b1 + b2, 1e-9f);
      g1r[t] = b1 / gs; g2r[t] = b2 / gs;
      idx1[t] = i1; idx2[t] = i2;
    }
    __syncthreads();
    if (threadIdx.x < NEXP) {
      float s = shm[NEXP*CDIM + 0*8 + threadIdx.x] + shm[NEXP*CDIM + 1*8 + threadIdx.x]
              + shm[NEXP*CDIM + 2*8 + threadIdx.x] + shm[NEXP*CDIM + 3*8 + threadIdx.x];
      impart[(size_t)rid*NEXP + threadIdx.x] = s;
    }
  }
}

// ---------------- scan: wave-shfl scans, 2 barriers in the hot path ----------
__global__ __launch_bounds__(1024) void scan_kernel(
    const int* __restrict__ idx1, const int* __restrict__ idx2,
    const float* __restrict__ g1r, const float* __restrict__ g2r,
    const float* __restrict__ impart,
    int* __restrict__ bufmap,
    int* __restrict__ c1o, int* __restrict__ c2o,
    float* __restrict__ g1o, float* __restrict__ g2o,
    float* __restrict__ aux_out) {
  __shared__ unsigned int wtot[16][NEXP];
  __shared__ unsigned int wscan[16][NEXP];
  __shared__ unsigned int totalsS[NEXP];
  __shared__ float fbuf[1024][NEXP+1];
  int tid = threadIdx.x;
  for (int i = tid; i < EROWS; i += 1024) bufmap[i] = -1;

  int e1[8], e2[8];
  unsigned int cnt[NEXP];
#pragma unroll
  for (int k = 0; k < NEXP; ++k) cnt[k] = 0;
  for (int j = 0; j < 8; ++j) {
    int t = tid*8 + j;
    e1[j] = idx1[t]; e2[j] = idx2[t];
    cnt[e1[j]] += 1u;            // lo16: first-choice, hi16: second-choice
    cnt[e2[j]] += (1u << 16);
  }
  int lane = tid & 63, wv = tid >> 6;
  unsigned int inc[NEXP];
#pragma unroll
  for (int k = 0; k < NEXP; ++k) inc[k] = cnt[k];
#pragma unroll
  for (int off = 1; off < 64; off <<= 1) {
#pragma unroll
    for (int k = 0; k < NEXP; ++k) {
      unsigned int v = __shfl_up(inc[k], off, 64);
      if (lane >= off) inc[k] += v;
    }
  }
  if (lane == 63) {
#pragma unroll
    for (int k = 0; k < NEXP; ++k) wtot[wv][k] = inc[k];
  }
  __syncthreads();
  if (tid < 16) {
    unsigned int v[NEXP];
#pragma unroll
    for (int k = 0; k < NEXP; ++k) v[k] = wtot[tid][k];
#pragma unroll
    for (int off = 1; off < 16; off <<= 1) {
#pragma unroll
      for (int k = 0; k < NEXP; ++k) {
        unsigned int s = __shfl_up(v[k], off, 16);
        if (tid >= off) v[k] += s;
      }
    }
#pragma unroll
    for (int k = 0; k < NEXP; ++k) wscan[tid][k] = v[k];
    if (tid == 15) {
#pragma unroll
      for (int k = 0; k < NEXP; ++k) totalsS[k] = v[k];
    }
  }
  __syncthreads();
  unsigned int excl[NEXP];
#pragma unroll
  for (int k = 0; k < NEXP; ++k)
    excl[k] = inc[k] - cnt[k] + (wv ? wscan[wv-1][k] : 0u);
  int cnt1c[NEXP];
#pragma unroll
  for (int k = 0; k < NEXP; ++k) cnt1c[k] = min((int)(totalsS[k] & 0xFFFFu), CAP);

  for (int j = 0; j < 8; ++j) {
    int t = tid*8 + j;
    int a = e1[j];
    int pos1 = (int)(excl[a] & 0xFFFFu); excl[a] += 1u;
    int slot1 = a*CAP + pos1;
    bool m1 = pos1 < CAP;
    if (m1) bufmap[slot1] = t;
    int b = e2[j];
    int pos2 = (int)(excl[b] >> 16) + cnt1c[b]; excl[b] += (1u << 16);
    int slot2 = b*CAP + pos2;
    bool m2 = pos2 < CAP;
    if (m2) bufmap[slot2] = t;
    float G1 = m1 ? g1r[t] : 0.f;
    float G2 = m2 ? g2r[t] : 0.f;
    float den = fmaxf(G1 + G2, 1e-9f);
    g1o[t] = G1 / den; g2o[t] = G2 / den;
    c1o[t] = min(slot1, EROWS - 1);
    c2o[t] = min(slot2, EROWS - 1);
  }

  // importance: sum 2048x8 router partials (deterministic fixed order)
  float imp[NEXP];
#pragma unroll
  for (int k = 0; k < NEXP; ++k)
    imp[k] = impart[(size_t)tid*NEXP + k] + impart[(size_t)(tid+1024)*NEXP + k];
  __syncthreads();
#pragma unroll
  for (int k = 0; k < NEXP; ++k) fbuf[tid][k] = imp[k];
  __syncthreads();
  for (int s = 512; s >= 1; s >>= 1) {
    if (tid < s) {
#pragma unroll
      for (int k = 0; k < NEXP; ++k) fbuf[tid][k] += fbuf[tid + s][k];
    }
    __syncthreads();
  }
  if (tid == 0) {
    float aux = 0.f;
#pragma unroll
    for (int k = 0; k < NEXP; ++k) {
      float importance = fbuf[0][k] / (float)NTOK;
      float loadk = (float)((totalsS[k] & 0xFFFFu) + (totalsS[k] >> 16)) / ((float)NTOK * 2.0f);
      aux += importance * loadk;
    }
    aux_out[0] = aux * (float)NEXP * 0.01f;
  }
}

// ---------------- dispatch: grid-stride gather x -> ein (bf16) ----------------
__global__ __launch_bounds__(256) void dispatch_kernel(const float* __restrict__ x,
    const int* __restrict__ bufmap, unsigned short* __restrict__ ein) {
  const int TOT = EROWS*(CDIM/4);
  for (int idx = blockIdx.x*256 + threadIdx.x; idx < TOT; idx += gridDim.x*256) {
    int r = idx / (CDIM/4), q = idx - r*(CDIM/4);
    int t = bufmap[r];
    float4 v = make_float4(0.f, 0.f, 0.f, 0.f);
    if (t >= 0) v = ((const float4*)x)[(size_t)t*(CDIM/4) + q];
    us4 o;
    o.x = f2b(v.x); o.y = f2b(v.y); o.z = f2b(v.z); o.w = f2b(v.w);
    ((us4*)ein)[(size_t)r*(CDIM/4) + q] = o;
  }
}

#define BAR  asm volatile("s_barrier" ::: "memory")
#define VMW(N) asm volatile("s_waitcnt vmcnt(" #N ")" ::: "memory")
#define LGW  asm volatile("s_waitcnt lgkmcnt(0)" ::: "memory")
#define P1 __builtin_amdgcn_s_setprio(1)
#define P0 __builtin_amdgcn_s_setprio(0)

// =============== GEMM1: persistent 256x256 8-phase (r9, verified 117us) ======
template<int KD>
__global__ __launch_bounds__(512, 2) void gemm1_8ph(
    const unsigned short* __restrict__ A,
    const unsigned short* __restrict__ Bw,
    unsigned short* __restrict__ H) {
  __shared__ unsigned short lds[81920];
  constexpr size_t JSTR = (size_t)6*256*KD;

  const int bid = blockIdx.x;
  const int chunk = gridDim.x >> 3;
  const int tile = (bid & 7)*chunk + (bid >> 3);
  const int e = tile / 30;
  const int r30 = tile % 30;
  const int ntb = r30 / 5, mt = r30 % 5;

  const int tid = threadIdx.x;
  const int l = tid & 63, wid = tid >> 6;
  const int wr = wid >> 2, wc = wid & 3;
  const int lrow = l & 15, khi = l >> 4;

  const unsigned short* Ab = A  + (size_t)e*CAP*KD      + (size_t)mt*256*KD;
  const unsigned short* Bb = Bw + (size_t)e*(2*IDIM)*KD + (size_t)ntb*256*KD;

  const int srow = tid >> 3;
  const int scol = (tid & 7) ^ (srow & 7);
  const size_t lane_off = (size_t)srow*KD + scol*8;
  const int lds_st = wid*512;

#define STG(dstu, srcp, half, kt) do { \
    const unsigned short* s_ = (srcp) + lane_off + (size_t)(half)*128*KD + (size_t)(kt)*64; \
    unsigned short* d_ = (unsigned short*)lds + (dstu) + (half)*8192 + lds_st; \
    __builtin_amdgcn_global_load_lds((const __attribute__((address_space(1))) void*)s_, \
        (__attribute__((address_space(3))) void*)d_, 16, 0, 0); \
    __builtin_amdgcn_global_load_lds((const __attribute__((address_space(1))) void*)(s_ + (size_t)64*KD), \
        (__attribute__((address_space(3))) void*)(d_ + 4096), 16, 0, 0); \
  } while(0)

  const int swz0 = ((khi    ) ^ (lrow & 7)) * 8;
  const int swz1 = ((4 + khi) ^ (lrow & 7)) * 8;
  const int aoff = wr*8192 + lrow*64;
  const int boff = (wc>>1)*8192 + ((wc&1)*64 + lrow)*64;

#define LDA(ab, dst, mb) do { _Pragma("unroll") for (int m_=0;m_<4;++m_) { \
    dst[m_][0] = *(const short8*)(lds + (ab) + aoff + ((mb)+m_)*1024 + swz0); \
    dst[m_][1] = *(const short8*)(lds + (ab) + aoff + ((mb)+m_)*1024 + swz1); } } while(0)
#define LDB(bb, dst, nb) do { _Pragma("unroll") for (int n_=0;n_<2;++n_) { \
    dst[n_][0] = *(const short8*)(lds + (bb) + boff + ((nb)+n_)*1024 + swz0); \
    dst[n_][1] = *(const short8*)(lds + (bb) + boff + ((nb)+n_)*1024 + swz1); } } while(0)
#define QUAD(af, bf, mb, nb) do { _Pragma("unroll") for (int r_=0;r_<2;++r_) \
    _Pragma("unroll") for (int n_=0;n_<2;++n_) \
    _Pragma("unroll") for (int m_=0;m_<4;++m_) \
      acc[(mb)+m_][(nb)+n_] = __builtin_amdgcn_mfma_f32_16x16x32_bf16(af[m_][r_], bf[n_][r_], acc[(mb)+m_][(nb)+n_], 0,0,0); } while(0)

  f32x4 acc[8][4];
#pragma unroll
  for (int i = 0; i < 8; ++i)
#pragma unroll
    for (int j = 0; j < 4; ++j) acc[i][j] = (f32x4){0.f,0.f,0.f,0.f};

  short8 a[4][2], bl[2][2], bh[2][2];

  int bA_ = 32768, bB_ = 49152, bC_ = 65536;

  STG(0, Ab, 0, 0);      STG(bA_, Bb, 0, 0);
  STG(0, Ab, 1, 0);      STG(bA_, Bb, 1, 0);
  STG(16384, Ab, 0, 1);  STG(bB_, Bb, 0, 1);
  STG(16384, Ab, 1, 1);  STG(bB_, Bb, 1, 1);
  VMW(8);
  BAR;

#define ITER(k2p, B2) \
    LDA(0, a, 0); LDB(bA_, bl, 0); STG(bC_, (B2), 0, (k2p)); \
    BAR; P1; QUAD(a, bl, 0, 0); P0; BAR; \
    LDB(bA_, bh, 2); STG(bC_, (B2), 1, (k2p)); \
    BAR; P1; QUAD(a, bh, 0, 2); P0; BAR; \
    LDA(0, a, 4); \
    BAR; P1; QUAD(a, bh, 4, 2); P0; BAR; \
    STG(0, Ab, 0, (k2p)); VMW(6); \
    BAR; P1; QUAD(a, bl, 4, 0); P0; BAR; \
    LDA(16384, a, 0); LDB(bB_, bl, 0); STG(0, Ab, 1, (k2p)); STG(bA_, (B2), 0, (k2p)+1); \
    BAR; P1; QUAD(a, bl, 0, 0); P0; BAR; \
    LDB(bB_, bh, 2); STG(bA_, (B2), 1, (k2p)+1); \
    BAR; P1; QUAD(a, bh, 0, 2); P0; BAR; \
    LDA(16384, a, 4); \
    BAR; P1; QUAD(a, bh, 4, 2); P0; BAR; \
    STG(16384, Ab, 0, (k2p)+1); STG(16384, Ab, 1, (k2p)+1); VMW(8); \
    BAR; P1; QUAD(a, bl, 4, 0); P0; BAR;

  const size_t rowg = (size_t)e*CAP + (size_t)mt*256;
  int itr = 0;

#pragma unroll 1
  for (int j = 0; j < 4; ++j) {
#pragma unroll 1
    for (int ii = 0; ii < 6; ++ii) {
      int t2 = 2*itr + 2;
      if (t2 >= 48) t2 = 0;                      // tail wrap (garbage stage)
      int j2 = t2 / 12, k2 = t2 - j2*12;
      const unsigned short* B2 = Bb + (size_t)j2*JSTR;
      ITER(k2, B2);
      int tmp = bC_; bC_ = bB_; bB_ = bA_; bA_ = tmp;
      ++itr;
    }
    {
      const size_t ntcol = (size_t)(ntb + 6*j)*128;
#pragma unroll
      for (int c = 0; c < 4; ++c) {
        BAR;
        if (wr == (c >> 1)) {
#pragma unroll
          for (int m_ = 0; m_ < 4; ++m_) {
#pragma unroll
            for (int p = 0; p < 2; ++p) {
              f32x4 g = acc[(c & 1)*4 + m_][2*p], u = acc[(c & 1)*4 + m_][2*p+1];
#pragma unroll
              for (int r = 0; r < 4; ++r) {
                float gv = g[r];
                float hv = gv / (1.f + __expf(-gv)) * u[r];
                lds[bC_ + (m_*16 + khi*4 + r)*136 + wc*32 + lrow + p*16] = f2b(hv);
              }
            }
          }
        }
        LGW;
        BAR;
#pragma unroll
        for (int q = 0; q < 2; ++q) {
          int idx = tid + 512*q;
          int rp = idx >> 4, ch = idx & 15;
          us8 v = *(const us8*)(lds + bC_ + rp*136 + ch*8);
          *(us8*)(H + (rowg + 64*c + rp)*(size_t)IDIM + ntcol + ch*8) = v;
        }
      }
      BAR;
    }
#pragma unroll
    for (int i2 = 0; i2 < 8; ++i2)
#pragma unroll
      for (int j2 = 0; j2 < 4; ++j2) acc[i2][j2] = (f32x4){0.f,0.f,0.f,0.f};
  }

#undef ITER
#undef QUAD
#undef LDB
#undef LDA
#undef STG
}

// =============== GEMM2: 256x128 8-phase deep pipeline (K=3072, 24 ITERs) =====
template<int KD>
__global__ __launch_bounds__(512, 2) void gemm2_8ph(
    const unsigned short* __restrict__ A,
    const unsigned short* __restrict__ Bw,
    unsigned short* __restrict__ O) {
  constexpr int NT = KD/64;        // 48
  constexpr int NITER = NT/2;      // 24
  __shared__ unsigned short lds[57344];

  const int bid = blockIdx.x;
  const int chunk = gridDim.x >> 3;
  const int tile = (bid & 7)*chunk + (bid >> 3);
  const int e = tile / 30;
  const int rem = tile % 30;
  const int nt = rem / 5, mt = rem % 5;

  const int tid = threadIdx.x;
  const int l = tid & 63, wid = tid >> 6;
  const int wr = wid >> 1, wc = wid & 1;
  const int lrow = l & 15, khi = l >> 4;

  const unsigned short* Ab = A  + (size_t)e*CAP*KD  + (size_t)mt*256*KD;
  const unsigned short* Bb = Bw + (size_t)e*CDIM*KD + (size_t)nt*128*KD;

  const int srow = tid >> 3;
  const int scol = (tid & 7) ^ (srow & 7);
  const size_t lane_off = (size_t)srow*KD + scol*8;
  const int lds_st = wid*512;

#define STG(dstu, srcp, half, kt) do { \
    const unsigned short* s_ = (srcp) + lane_off + (size_t)(half)*128*KD + (size_t)(kt)*64; \
    unsigned short* d_ = (unsigned short*)lds + (dstu) + (half)*8192 + lds_st; \
    __builtin_amdgcn_global_load_lds((const __attribute__((address_space(1))) void*)s_, \
        (__attribute__((address_space(3))) void*)d_, 16, 0, 0); \
    __builtin_amdgcn_global_load_lds((const __attribute__((address_space(1))) void*)(s_ + (size_t)64*KD), \
        (__attribute__((address_space(3))) void*)(d_ + 4096), 16, 0, 0); \
  } while(0)

  const int swz0 = ((khi    ) ^ (lrow & 7)) * 8;
  const int swz1 = ((4 + khi) ^ (lrow & 7)) * 8;
  const int aoff = wr*4096 + lrow*64;
  const int boff = wc*4096 + lrow*64;

#define LDA(ab, dst) do { _Pragma("unroll") for (int m_=0;m_<4;++m_) { \
    dst[m_][0] = *(const short8*)(lds + (ab) + aoff + m_*1024 + swz0); \
    dst[m_][1] = *(const short8*)(lds + (ab) + aoff + m_*1024 + swz1); } } while(0)
#define LDB(bb, dst, nb) do { _Pragma("unroll") for (int n_=0;n_<2;++n_) { \
    dst[n_][0] = *(const short8*)(lds + (bb) + boff + ((nb)+n_)*1024 + swz0); \
    dst[n_][1] = *(const short8*)(lds + (bb) + boff + ((nb)+n_)*1024 + swz1); } } while(0)
#define QUAD(af, bf, nb) do { _Pragma("unroll") for (int r_=0;r_<2;++r_) \
    _Pragma("unroll") for (int n_=0;n_<2;++n_) \
    _Pragma("unroll") for (int m_=0;m_<4;++m_) \
      acc[m_][(nb)+n_] = __builtin_amdgcn_mfma_f32_16x16x32_bf16(af[m_][r_], bf[n_][r_], acc[m_][(nb)+n_], 0,0,0); } while(0)

  f32x4 acc[4][4];
#pragma unroll
  for (int i = 0; i < 4; ++i)
#pragma unroll
    for (int j = 0; j < 4; ++j) acc[i][j] = (f32x4){0.f,0.f,0.f,0.f};

  short8 a[4][2], bl[2][2], bh[2][2];

  int bA_ = 32768, bB_ = 40960, bC_ = 49152;

  STG(0, Ab, 0, 0); STG(0, Ab, 1, 0); STG(bA_, Bb, 0, 0);
  STG(16384, Ab, 0, 1); STG(16384, Ab, 1, 1); STG(bB_, Bb, 0, 1);
  VMW(6);
  BAR;

#define ITER2(t2, t3, DOS, VM2, VM4) \
    LDA(0, a); LDB(bA_, bl, 0); if (DOS) STG(bC_, Bb, 0, (t2)); \
    BAR; P1; QUAD(a, bl, 0); P0; BAR; \
    LDB(bA_, bh, 2); if (DOS) { STG(0, Ab, 0, (t2)); STG(0, Ab, 1, (t2)); } VM2; \
    BAR; P1; QUAD(a, bh, 2); P0; BAR; \
    LDA(16384, a); LDB(bB_, bl, 0); if (DOS) STG(bA_, Bb, 0, (t3)); \
    BAR; P1; QUAD(a, bl, 0); P0; BAR; \
    LDB(bB_, bh, 2); if (DOS) { STG(16384, Ab, 0, (t3)); STG(16384, Ab, 1, (t3)); } VM4; \
    BAR; P1; QUAD(a, bh, 2); P0; BAR;

#pragma unroll 1
  for (int i = 0; i < NITER-1; ++i) {
    const int t2 = 2*i+2, t3 = 2*i+3;
    ITER2(t2, t3, true, VMW(6), VMW(6));
    int tmp = bC_; bC_ = bB_; bB_ = bA_; bA_ = tmp;
  }
  ITER2(0, 0, false, VMW(0), VMW(0));

#undef ITER2
#undef QUAD
#undef LDB
#undef LDA
#undef STG

  __syncthreads();
  {
    const int cb0 = wc*64 + lrow;
    const int rb0 = wr*64 + khi*4;
#pragma unroll
    for (int m = 0; m < 4; ++m)
#pragma unroll
      for (int n = 0; n < 4; ++n) {
        f32x4 v = acc[m][n];
#pragma unroll
        for (int r = 0; r < 4; ++r)
          lds[(rb0 + m*16 + r)*136 + cb0 + n*16] = f2b(v[r]);
      }
  }
  __syncthreads();
  const size_t rowg = (size_t)e*CAP + (size_t)mt*256;
  const size_t colg = (size_t)nt*128 + (size_t)(l & 15)*8;
#pragma unroll
  for (int i = 0; i < 8; ++i) {
    int row = wid*32 + i*4 + (l >> 4);
    us8 v = *(const us8*)(lds + row*136 + (l & 15)*8);
    *(us8*)(O + (rowg + row)*(size_t)CDIM + colg) = v;
  }
}

// ---------------- combine: grid-stride (bf16 expert outputs -> f32 y) --------
__global__ __launch_bounds__(256) void combine_kernel(const unsigned short* __restrict__ outbuf,
    const int* __restrict__ c1, const int* __restrict__ c2,
    const float* __restrict__ g1, const float* __restrict__ g2,
    float* __restrict__ y) {
  const int TOT = NTOK*(CDIM/4);
  for (int idx = blockIdx.x*256 + threadIdx.x; idx < TOT; idx += gridDim.x*256) {
    int t = idx / (CDIM/4), q = idx - t*(CDIM/4);
    float f1 = g1[t], f2 = g2[t];
    int a = c1[t], b = c2[t];
    us4 va = ((const us4*)outbuf)[(size_t)a*(CDIM/4) + q];
    us4 vb = ((const us4*)outbuf)[(size_t)b*(CDIM/4) + q];
    float4 r;
    r.x = f1*b2f(va.x) + f2*b2f(vb.x);
    r.y = f1*b2f(va.y) + f2*b2f(vb.y);
    r.z = f1*b2f(va.z) + f2*b2f(vb.z);
    r.w = f1*b2f(va.w) + f2*b2f(vb.w);
    ((float4*)y)[(size_t)t*(CDIM/4) + q] = r;
  }
}

extern "C" void kernel_launch(void* const* d_in, const int* in_sizes, int n_in,
                              void* d_out, int out_size, void* d_ws, size_t ws_size,
                              hipStream_t stream) {
  const float* x  = (const float*)d_in[0];
  const float* Wr = (const float*)d_in[1];
  const float* Wg = (const float*)d_in[2];
  const float* Wu = (const float*)d_in[3];
  const float* Wp = (const float*)d_in[4];
  float* y = (float*)d_out;

  char* p = (char*)d_ws;
  auto alloc = [&](size_t bytes) { char* r = p; p += (bytes + 255) & ~(size_t)255; return r; };
  unsigned short* WguT = (unsigned short*)alloc((size_t)NEXP*2*IDIM*CDIM*2);
  unsigned short* WpT  = (unsigned short*)alloc((size_t)NEXP*CDIM*IDIM*2);
  unsigned short* ein  = (unsigned short*)alloc((size_t)EROWS*CDIM*2);
  unsigned short* h    = (unsigned short*)alloc((size_t)EROWS*IDIM*2);
  unsigned short* outbuf = (unsigned short*)alloc((size_t)EROWS*CDIM*2);
  float* impart = (float*)alloc((size_t)(NTOK/4)*NEXP*4);
  int* idx1 = (int*)alloc(NTOK*4);
  int* idx2 = (int*)alloc(NTOK*4);
  int* c1   = (int*)alloc(NTOK*4);
  int* c2   = (int*)alloc(NTOK*4);
  float* g1r = (float*)alloc(NTOK*4);
  float* g2r = (float*)alloc(NTOK*4);
  float* g1o = (float*)alloc(NTOK*4);
  float* g2o = (float*)alloc(NTOK*4);
  int* bufmap = (int*)alloc(EROWS*4);

  size_t required = (size_t)(p - (char*)d_ws);
  if (ws_size < required) return;

  const int NWGU = 2*NEXP*(CDIM/64)*(IDIM/64);   // 9216
  const int NWP  = NEXP*(IDIM/64)*(CDIM/64);     // 4608
  prep_kernel<<<NWGU + NWP + NTOK/4, 256, 0, stream>>>(
      Wg, Wu, Wp, x, Wr, WguT, WpT, impart, idx1, idx2, g1r, g2r);

  scan_kernel<<<1, 1024, 0, stream>>>(idx1, idx2, g1r, g2r, impart, bufmap,
                                      c1, c2, g1o, g2o, y + (size_t)NTOK*CDIM);
  dispatch_kernel<<<2048, 256, 0, stream>>>(x, bufmap, ein);

  gemm1_8ph<CDIM><<<240, 512, 0, stream>>>(ein, WguT, h);
  gemm2_8ph<IDIM><<<NEXP*5*(CDIM/128), 512, 0, stream>>>(h, WpT, outbuf);

  combine_kernel<<<2048, 256, 0, stream>>>(outbuf, c1, c2, g1o, g2o, y);
}